// Round 10
// baseline (234.062 us; speedup 1.0000x reference)
//
#include <hip/hip_runtime.h>
#include <hip/hip_fp16.h>
#include <math.h>

#define HH 32
#define WW 32
#define HWSZ 1024      // H*W
#define CC 384
#define NHEAD 12
#define NGROUP 6
#define HC 32
#define GC 64
#define NS 1024        // n_sample
#define ATTN_SCALE 0.17677669529663687f  // 32^-0.5

typedef _Float16 half8_t __attribute__((ext_vector_type(8)));
typedef _Float16 half4_t __attribute__((ext_vector_type(4)));
typedef _Float16 half2_t __attribute__((ext_vector_type(2)));
typedef float    f4_t    __attribute__((ext_vector_type(4)));

// ---------------------------------------------------------------------------
// MFMA GEMM (fp32 in/out via f16 hi/lo splits, 3 MFMAs per product).
// Y[b,o,n] = sum_c W[o,c] X[b,c,n] + bias[o].  Tile M=32, N=64, BK=32.
// Block 256 thr (4 waves): wave w owns n-cols [w*16,+16), all 32 m-rows.
// Frags (16x16x32 f16): A[m=lane&15][k=quad*8+j], B[k][n=lane&15],
// C/D[row=quad*4+reg][col=lane&15].
// ---------------------------------------------------------------------------
__global__ __launch_bounds__(256) void gemm_mfma_qo(
    const float* __restrict__ W, const float* __restrict__ bias,
    const float* __restrict__ X, float* __restrict__ Y)
{
    const int bz = blockIdx.z;
    const int tm = blockIdx.y * 32;
    const int tn = blockIdx.x * 64;
    const int tid = threadIdx.x;
    const int w = tid >> 6, lane = tid & 63;
    const int quad = lane >> 4, lcol = lane & 15;

    __shared__ _Float16 sWh[32][40], sWl[32][40];   // W tile hi/lo [m][k]
    __shared__ _Float16 sXh[64][40], sXl[64][40];   // X tile hi/lo [n][k]

    const float* Xb = X + (size_t)bz * CC * 1024;
    float* Yb = Y + (size_t)bz * CC * 1024;

    f4_t acc0 = {0.f, 0.f, 0.f, 0.f}, acc1 = {0.f, 0.f, 0.f, 0.f};

    for (int k0 = 0; k0 < CC; k0 += 32) {
        {   // stage W 32m x 32k (coalesced float4)
            int m = tid >> 3, k4 = (tid & 7) * 4;
            float4 wv = *(const float4*)&W[(size_t)(tm + m) * CC + k0 + k4];
            float vv[4] = {wv.x, wv.y, wv.z, wv.w};
#pragma unroll
            for (int i = 0; i < 4; ++i) {
                _Float16 h = (_Float16)vv[i];
                sWh[m][k4 + i] = h;
                sWl[m][k4 + i] = (_Float16)(vv[i] - (float)h);
            }
        }
        {   // stage X 32k x 64n -> transposed [n][k] (coalesced float4 loads)
            int k = tid >> 3, n8 = (tid & 7) * 8;
            float4 xa = *(const float4*)&Xb[(size_t)(k0 + k) * 1024 + tn + n8];
            float4 xc = *(const float4*)&Xb[(size_t)(k0 + k) * 1024 + tn + n8 + 4];
            float vv[8] = {xa.x, xa.y, xa.z, xa.w, xc.x, xc.y, xc.z, xc.w};
#pragma unroll
            for (int i = 0; i < 8; ++i) {
                _Float16 h = (_Float16)vv[i];
                sXh[n8 + i][k] = h;
                sXl[n8 + i][k] = (_Float16)(vv[i] - (float)h);
            }
        }
        __syncthreads();

        half8_t Ah0 = *(const half8_t*)&sWh[lcol][quad * 8];
        half8_t Al0 = *(const half8_t*)&sWl[lcol][quad * 8];
        half8_t Ah1 = *(const half8_t*)&sWh[16 + lcol][quad * 8];
        half8_t Al1 = *(const half8_t*)&sWl[16 + lcol][quad * 8];
        half8_t Bh  = *(const half8_t*)&sXh[w * 16 + lcol][quad * 8];
        half8_t Bl  = *(const half8_t*)&sXl[w * 16 + lcol][quad * 8];

        acc0 = __builtin_amdgcn_mfma_f32_16x16x32_f16(Ah0, Bl, acc0, 0, 0, 0);
        acc0 = __builtin_amdgcn_mfma_f32_16x16x32_f16(Al0, Bh, acc0, 0, 0, 0);
        acc0 = __builtin_amdgcn_mfma_f32_16x16x32_f16(Ah0, Bh, acc0, 0, 0, 0);
        acc1 = __builtin_amdgcn_mfma_f32_16x16x32_f16(Ah1, Bl, acc1, 0, 0, 0);
        acc1 = __builtin_amdgcn_mfma_f32_16x16x32_f16(Al1, Bh, acc1, 0, 0, 0);
        acc1 = __builtin_amdgcn_mfma_f32_16x16x32_f16(Ah1, Bh, acc1, 0, 0, 0);
        __syncthreads();
    }

#pragma unroll
    for (int r = 0; r < 4; ++r) {
        int m0 = tm + quad * 4 + r;
        Yb[(size_t)m0 * 1024 + tn + w * 16 + lcol]        = acc0[r] + bias[m0];
        Yb[(size_t)(m0 + 16) * 1024 + tn + w * 16 + lcol] = acc1[r] + bias[m0 + 16];
    }
}

// ---------------------------------------------------------------------------
// MFMA K/V projection. Same staging; per-`which` frag roles:
//   V (which=1): D[hc][n] = W·X  -> vhb [bh][hc][n]
//   K (which=0): D[n][hc] = X^T·W^T (A from X, B from W) -> khT [bh][n][hc]
// f16 outputs, grid (16, head=12, batch*2+which).
// ---------------------------------------------------------------------------
__global__ __launch_bounds__(256) void gemm_mfma_kv(
    const float* __restrict__ Wk, const float* __restrict__ bk,
    const float* __restrict__ Wv, const float* __restrict__ bv,
    const float* __restrict__ X,
    _Float16* __restrict__ khT, _Float16* __restrict__ vhb)
{
    const int bz = blockIdx.z >> 1, which = blockIdx.z & 1;
    const int head = blockIdx.y;
    const int tm = head * 32;
    const int tn = blockIdx.x * 64;
    const int tid = threadIdx.x;
    const int w = tid >> 6, lane = tid & 63;
    const int quad = lane >> 4, lcol = lane & 15;
    const int bh = bz * 12 + head;

    const float* W    = which ? Wv : Wk;
    const float* bias = which ? bv : bk;

    __shared__ _Float16 sWh[32][40], sWl[32][40];
    __shared__ _Float16 sXh[64][40], sXl[64][40];

    const float* Xb = X + (size_t)bz * CC * 1024;

    f4_t acc0 = {0.f, 0.f, 0.f, 0.f}, acc1 = {0.f, 0.f, 0.f, 0.f};

    for (int k0 = 0; k0 < CC; k0 += 32) {
        {
            int m = tid >> 3, k4 = (tid & 7) * 4;
            float4 wv = *(const float4*)&W[(size_t)(tm + m) * CC + k0 + k4];
            float vv[4] = {wv.x, wv.y, wv.z, wv.w};
#pragma unroll
            for (int i = 0; i < 4; ++i) {
                _Float16 h = (_Float16)vv[i];
                sWh[m][k4 + i] = h;
                sWl[m][k4 + i] = (_Float16)(vv[i] - (float)h);
            }
        }
        {
            int k = tid >> 3, n8 = (tid & 7) * 8;
            float4 xa = *(const float4*)&Xb[(size_t)(k0 + k) * 1024 + tn + n8];
            float4 xc = *(const float4*)&Xb[(size_t)(k0 + k) * 1024 + tn + n8 + 4];
            float vv[8] = {xa.x, xa.y, xa.z, xa.w, xc.x, xc.y, xc.z, xc.w};
#pragma unroll
            for (int i = 0; i < 8; ++i) {
                _Float16 h = (_Float16)vv[i];
                sXh[n8 + i][k] = h;
                sXl[n8 + i][k] = (_Float16)(vv[i] - (float)h);
            }
        }
        __syncthreads();

        if (which) {   // V: A=W rows, B=X col-group w
            half8_t Ah0 = *(const half8_t*)&sWh[lcol][quad * 8];
            half8_t Al0 = *(const half8_t*)&sWl[lcol][quad * 8];
            half8_t Ah1 = *(const half8_t*)&sWh[16 + lcol][quad * 8];
            half8_t Al1 = *(const half8_t*)&sWl[16 + lcol][quad * 8];
            half8_t Bh  = *(const half8_t*)&sXh[w * 16 + lcol][quad * 8];
            half8_t Bl  = *(const half8_t*)&sXl[w * 16 + lcol][quad * 8];
            acc0 = __builtin_amdgcn_mfma_f32_16x16x32_f16(Ah0, Bl, acc0, 0, 0, 0);
            acc0 = __builtin_amdgcn_mfma_f32_16x16x32_f16(Al0, Bh, acc0, 0, 0, 0);
            acc0 = __builtin_amdgcn_mfma_f32_16x16x32_f16(Ah0, Bh, acc0, 0, 0, 0);
            acc1 = __builtin_amdgcn_mfma_f32_16x16x32_f16(Ah1, Bl, acc1, 0, 0, 0);
            acc1 = __builtin_amdgcn_mfma_f32_16x16x32_f16(Al1, Bh, acc1, 0, 0, 0);
            acc1 = __builtin_amdgcn_mfma_f32_16x16x32_f16(Ah1, Bh, acc1, 0, 0, 0);
        } else {       // K: A=X n-rows (wave w), B=W hc col-groups
            half8_t Ah = *(const half8_t*)&sXh[w * 16 + lcol][quad * 8];
            half8_t Al = *(const half8_t*)&sXl[w * 16 + lcol][quad * 8];
            half8_t Bh0 = *(const half8_t*)&sWh[lcol][quad * 8];
            half8_t Bl0 = *(const half8_t*)&sWl[lcol][quad * 8];
            half8_t Bh1 = *(const half8_t*)&sWh[16 + lcol][quad * 8];
            half8_t Bl1 = *(const half8_t*)&sWl[16 + lcol][quad * 8];
            acc0 = __builtin_amdgcn_mfma_f32_16x16x32_f16(Ah, Bl0, acc0, 0, 0, 0);
            acc0 = __builtin_amdgcn_mfma_f32_16x16x32_f16(Al, Bh0, acc0, 0, 0, 0);
            acc0 = __builtin_amdgcn_mfma_f32_16x16x32_f16(Ah, Bh0, acc0, 0, 0, 0);
            acc1 = __builtin_amdgcn_mfma_f32_16x16x32_f16(Ah, Bl1, acc1, 0, 0, 0);
            acc1 = __builtin_amdgcn_mfma_f32_16x16x32_f16(Al, Bh1, acc1, 0, 0, 0);
            acc1 = __builtin_amdgcn_mfma_f32_16x16x32_f16(Ah, Bh1, acc1, 0, 0, 0);
        }
        __syncthreads();
    }

    if (which) {   // V epilogue: [bh][hc][n]
#pragma unroll
        for (int r = 0; r < 4; ++r) {
            int hc0 = quad * 4 + r;
            vhb[((size_t)bh * 32 + hc0) * 1024 + tn + w * 16 + lcol] =
                (_Float16)(acc0[r] + bias[tm + hc0]);
            vhb[((size_t)bh * 32 + hc0 + 16) * 1024 + tn + w * 16 + lcol] =
                (_Float16)(acc1[r] + bias[tm + hc0 + 16]);
        }
    } else {       // K epilogue: [bh][n][hc]
        float bk0 = bias[tm + lcol], bk1 = bias[tm + 16 + lcol];
#pragma unroll
        for (int r = 0; r < 4; ++r) {
            int n = tn + w * 16 + quad * 4 + r;
            khT[((size_t)bh * 1024 + n) * 32 + lcol]      = (_Float16)(acc0[r] + bk0);
            khT[((size_t)bh * 1024 + n) * 32 + 16 + lcol] = (_Float16)(acc1[r] + bk1);
        }
    }
}

// ---------------------------------------------------------------------------
// Depthwise 7x7 conv on q viewed as [12, 64, 32, 32]; zero pad 3.
// ---------------------------------------------------------------------------
__global__ __launch_bounds__(256) void dwconv_kernel(
    const float* __restrict__ q, const float* __restrict__ dww,
    const float* __restrict__ dwb, float* __restrict__ oconv)
{
    const int bc = blockIdx.x;
    const int bg = bc >> 6, c = bc & 63;
    const int b = bg / 6, g = bg % 6;
    const float* plane = q + ((size_t)b * CC + g * 64 + c) * 1024;

    __shared__ float sp[1024];
    __shared__ float sw[49];
    const int tid = threadIdx.x;
    for (int i = tid; i < 1024; i += 256) sp[i] = plane[i];
    if (tid < 49) sw[tid] = dww[c * 49 + tid];
    __syncthreads();

    const float bias = dwb[c];
    for (int i = tid; i < 1024; i += 256) {
        int y = i >> 5, x = i & 31;
        float s = 0.f;
#pragma unroll
        for (int ky = 0; ky < 7; ++ky) {
            int yy = y + ky - 3;
            if (yy < 0 || yy > 31) continue;
#pragma unroll
            for (int kx = 0; kx < 7; ++kx) {
                int xx = x + kx - 3;
                if (xx < 0 || xx > 31) continue;
                s += sp[yy * 32 + xx] * sw[ky * 7 + kx];
            }
        }
        oconv[(size_t)bc * 1024 + i] = s + bias;
    }
}

// ---------------------------------------------------------------------------
// LayerNorm(64 ch) + exact GELU + 1x1->2ch + tanh*2/32 + ref points.
// ---------------------------------------------------------------------------
__global__ __launch_bounds__(256) void offset_kernel(
    const float* __restrict__ oconv, const float* __restrict__ lng,
    const float* __restrict__ lnb, const float* __restrict__ pw,
    float* __restrict__ pos)
{
    const int bg = blockIdx.x;
    const int px = blockIdx.y * 256 + threadIdx.x;
    const float* base = oconv + (size_t)bg * 64 * 1024 + px;

    float col[64];
    float sum = 0.f;
#pragma unroll
    for (int c = 0; c < 64; ++c) { col[c] = base[(size_t)c * 1024]; sum += col[c]; }
    float mu = sum * (1.f / 64.f);
    float var = 0.f;
#pragma unroll
    for (int c = 0; c < 64; ++c) { float d = col[c] - mu; var += d * d; }
    float inv = rsqrtf(var * (1.f / 64.f) + 1e-5f);
    float offy = 0.f, offx = 0.f;
#pragma unroll
    for (int c = 0; c < 64; ++c) {
        float v = (col[c] - mu) * inv * lng[c] + lnb[c];
        float g = 0.5f * v * (1.f + erff(v * 0.70710678118654752440f));
        offy += g * pw[c];
        offx += g * pw[64 + c];
    }
    offy = tanhf(offy) * (2.0f / 32.0f);
    offx = tanhf(offx) * (2.0f / 32.0f);
    int y = px >> 5, x = px & 31;
    float ry = ((y + 0.5f) / 32.f) * 2.f - 1.f;
    float rx = ((x + 0.5f) / 32.f) * 2.f - 1.f;
    pos[((size_t)bg * 1024 + px) * 2 + 0] = offy + ry;
    pos[((size_t)bg * 1024 + px) * 2 + 1] = offx + rx;
}

// ---------------------------------------------------------------------------
// Bilinear grid-sample of x at pos (align_corners=True, zeros pad).
// ---------------------------------------------------------------------------
__global__ __launch_bounds__(256) void sample_kernel(
    const float* __restrict__ x, const float* __restrict__ pos,
    float* __restrict__ xs)
{
    const int idx = blockIdx.x * 256 + threadIdx.x;
    const int s = idx & 1023;
    const int bc = idx >> 10;
    const int c = bc % CC;
    const int b = bc / CC;
    const int bg = b * 6 + (c >> 6);

    float py = pos[((size_t)bg * 1024 + s) * 2 + 0];
    float px = pos[((size_t)bg * 1024 + s) * 2 + 1];
    float gx = (px + 1.f) * 0.5f * 31.f;
    float gy = (py + 1.f) * 0.5f * 31.f;
    float x0f = floorf(gx), y0f = floorf(gy);
    float wx = gx - x0f, wy = gy - y0f;
    int x0 = (int)x0f, y0 = (int)y0f;

    const float* plane = x + (size_t)bc * 1024;
    float acc = 0.f;
    if ((unsigned)x0       <= 31u && (unsigned)y0       <= 31u) acc += plane[y0 * 32 + x0]           * (1.f - wx) * (1.f - wy);
    if ((unsigned)(x0 + 1) <= 31u && (unsigned)y0       <= 31u) acc += plane[y0 * 32 + x0 + 1]       * wx * (1.f - wy);
    if ((unsigned)x0       <= 31u && (unsigned)(y0 + 1) <= 31u) acc += plane[(y0 + 1) * 32 + x0]     * (1.f - wx) * wy;
    if ((unsigned)(x0 + 1) <= 31u && (unsigned)(y0 + 1) <= 31u) acc += plane[(y0 + 1) * 32 + x0 + 1] * wx * wy;
    xs[idx] = acc;
}

// ---------------------------------------------------------------------------
// MFMA flash attention, transposed dataflow (S^T = K·Q^T), K-split 4 waves.
// R10: RPE table as scalar f16 (8KB, stride-64 rows, 4 u16 taps) and combine
// buffer aliasing each wave's own P slab -> LDS 18.8KB -> 8 blocks/CU.
// ---------------------------------------------------------------------------
__global__ __launch_bounds__(256) void attn_mfma_kernel(
    const float* __restrict__ q, const _Float16* __restrict__ khT,
    const _Float16* __restrict__ vhb, const float* __restrict__ pos,
    const float* __restrict__ rpe, float* __restrict__ out)
{
    const int bh = blockIdx.y;
    const int b = bh / 12, head = bh % 12;
    const int bg = b * 6 + (head >> 1);
    const int mblk = blockIdx.x * 16;      // 16 queries, one image row
    const int tid = threadIdx.x;
    const int w = tid >> 6, lane = tid & 63;
    const int quad = lane >> 4, lcol = lane & 15;

    // LDS: srpe @0 (8064B), sqh @8064 (1024B), sp @9088 (4x2304B),
    //      cml @18304 (512B).  comb aliases sp (wave w combine slab == its
    //      own P slab, written only after its last P read).
    __shared__ __align__(16) char smem[18816];
    _Float16* srpe = (_Float16*)smem;                       // [63 rows][64]
    _Float16* sqh  = (_Float16*)(smem + 8064);
    _Float16* spw  = (_Float16*)(smem + 9088) + w * (16 * 72);
    float*    cml  = (float*)(smem + 18304);
    float*    comb = (float*)(smem + 9088);

    const float* rp = rpe + (size_t)head * 3969;
    for (int i = tid; i < 3969; i += 256) {
        int y = i / 63, x = i - y * 63;
        srpe[y * 64 + x] = (_Float16)rp[i];
    }
    {
        const float* qb = q + ((size_t)b * CC + head * 32) * 1024 + mblk;
        for (int i = tid; i < 512; i += 256) {
            int hc = i >> 4, m = i & 15;
            sqh[m * 32 + hc] = (_Float16)qb[(size_t)hc * 1024 + m];
        }
    }
    __syncthreads();

    // Q^T B-frag: B[k=hc=quad*8+j][n=query=lcol]
    half8_t qf = *(const half8_t*)&sqh[lcol * 32 + quad * 8];

    const float qyw = (((mblk >> 5) + 0.5f) * (1.f / 32.f)) * 2.f - 1.f;
    const float qx  = (((mblk & 31) + lcol + 0.5f) * (1.f / 32.f)) * 2.f - 1.f;

    const float2* pgv = (const float2*)(pos + (size_t)bg * 2048);
    const _Float16* khb = khT + (size_t)bh * 1024 * 32;
    const _Float16* vhh = vhb + (size_t)bh * 32 * 1024;

    f4_t o0 = {0.f, 0.f, 0.f, 0.f}, o1 = {0.f, 0.f, 0.f, 0.f};
    float mrun = -3.0e38f, lrun = 0.f;     // per-lane query state

#pragma unroll 1
    for (int c = 0; c < 4; ++c) {
        const int n0 = w * 256 + c * 64;
        f4_t S[4];
#pragma unroll
        for (int t = 0; t < 4; ++t) {
            half8_t kh = *(const half8_t*)&khb[(size_t)(n0 + t * 16 + lcol) * 32 + quad * 8];
            f4_t s = {0.f, 0.f, 0.f, 0.f};
            s = __builtin_amdgcn_mfma_f32_16x16x32_f16(kh, qf, s, 0, 0, 0);
#pragma unroll
            for (int r = 0; r < 4; ++r) {
                int key = n0 + t * 16 + quad * 4 + r;
                float2 pp = pgv[key];
                float gy = (qyw - pp.x) * 15.5f + 31.f;
                float gx = (qx  - pp.y) * 15.5f + 31.f;
                float y0f = floorf(gy), x0f = floorf(gx);
                float wy = gy - y0f, wx = gx - x0f;
                int i00 = (int)y0f * 64 + (int)x0f;
                float r00 = (float)srpe[i00],      r01 = (float)srpe[i00 + 1];
                float r10 = (float)srpe[i00 + 64], r11 = (float)srpe[i00 + 65];
                float top = r00 + (r01 - r00) * wx;
                float bot = r10 + (r11 - r10) * wx;
                s[r] = s[r] * ATTN_SCALE + top + (bot - top) * wy;
            }
            S[t] = s;
        }

        // online softmax for this chunk (per-lane query; reduce keys)
        float cm = -3.0e38f;
#pragma unroll
        for (int t = 0; t < 4; ++t)
            cm = fmaxf(cm, fmaxf(fmaxf(S[t][0], S[t][1]), fmaxf(S[t][2], S[t][3])));
        cm = fmaxf(cm, __shfl_xor(cm, 16));
        cm = fmaxf(cm, __shfl_xor(cm, 32));
        float mnew = fmaxf(mrun, cm);
        float alpha = __expf(mrun - mnew);
        mrun = mnew;

        float rs = 0.f;
#pragma unroll
        for (int t = 0; t < 4; ++t) {
            float p0 = __expf(S[t][0] - mnew);
            float p1 = __expf(S[t][1] - mnew);
            float p2 = __expf(S[t][2] - mnew);
            float p3 = __expf(S[t][3] - mnew);
            rs += (p0 + p1) + (p2 + p3);
            half4_t h;
            h[0] = (_Float16)p0; h[1] = (_Float16)p1;
            h[2] = (_Float16)p2; h[3] = (_Float16)p3;
            *(half4_t*)&spw[lcol * 72 + t * 16 + quad * 4] = h;   // P^T[query][key]
        }
        rs += __shfl_xor(rs, 16);
        rs += __shfl_xor(rs, 32);
        lrun = lrun * alpha + rs;
        o0 *= alpha; o1 *= alpha;

        // PV: O^T += V^T · P^T  (wave-internal LDS read-back; no barrier)
#pragma unroll
        for (int kp = 0; kp < 2; ++kp) {
            half8_t pb = *(const half8_t*)&spw[lcol * 72 + kp * 32 + quad * 8];
            int nb = n0 + kp * 32 + quad * 8;
            half8_t v0 = *(const half8_t*)&vhh[(size_t)lcol * 1024 + nb];
            half8_t v1 = *(const half8_t*)&vhh[(size_t)(16 + lcol) * 1024 + nb];
            o0 = __builtin_amdgcn_mfma_f32_16x16x32_f16(v0, pb, o0, 0, 0, 0);
            o1 = __builtin_amdgcn_mfma_f32_16x16x32_f16(v1, pb, o1, 0, 0, 0);
        }
    }

    __syncthreads();   // everyone done with their P slab -> alias as comb

    // O^T D-layout: o0[r]=O^T[hc=quad*4+r][query=lcol], o1: hc+16
    *(f4_t*)&comb[(w * 16 + lcol) * 36 + quad * 4]      = o0;
    *(f4_t*)&comb[(w * 16 + lcol) * 36 + 16 + quad * 4] = o1;
    if (quad == 0) {
        cml[(w * 16 + lcol) * 2]     = mrun;
        cml[(w * 16 + lcol) * 2 + 1] = lrun;
    }
    __syncthreads();

#pragma unroll
    for (int i = 0; i < 2; ++i) {
        int idx = tid + i * 256;
        int qq = idx >> 5, hc = idx & 31;
        float m0 = cml[(0 * 16 + qq) * 2], l0 = cml[(0 * 16 + qq) * 2 + 1];
        float m1 = cml[(1 * 16 + qq) * 2], l1 = cml[(1 * 16 + qq) * 2 + 1];
        float m2 = cml[(2 * 16 + qq) * 2], l2 = cml[(2 * 16 + qq) * 2 + 1];
        float m3 = cml[(3 * 16 + qq) * 2], l3 = cml[(3 * 16 + qq) * 2 + 1];
        float ms = fmaxf(fmaxf(m0, m1), fmaxf(m2, m3));
        float e0 = __expf(m0 - ms), e1 = __expf(m1 - ms);
        float e2 = __expf(m2 - ms), e3 = __expf(m3 - ms);
        float L = e0 * l0 + e1 * l1 + e2 * l2 + e3 * l3;
        float o = e0 * comb[(0 * 16 + qq) * 36 + hc]
                + e1 * comb[(1 * 16 + qq) * 36 + hc]
                + e2 * comb[(2 * 16 + qq) * 36 + hc]
                + e3 * comb[(3 * 16 + qq) * 36 + hc];
        out[((size_t)b * CC + head * 32 + hc) * 1024 + mblk + qq] = o / L;
    }
}

// ---------------------------------------------------------------------------
extern "C" void kernel_launch(void* const* d_in, const int* in_sizes, int n_in,
                              void* d_out, int out_size, void* d_ws, size_t ws_size,
                              hipStream_t stream) {
    const float* x   = (const float*)d_in[0];
    const float* Wq  = (const float*)d_in[1];
    const float* bq  = (const float*)d_in[2];
    const float* Wk  = (const float*)d_in[3];
    const float* bk  = (const float*)d_in[4];
    const float* Wv  = (const float*)d_in[5];
    const float* bv  = (const float*)d_in[6];
    const float* Wo  = (const float*)d_in[7];
    const float* bo  = (const float*)d_in[8];
    const float* dww = (const float*)d_in[9];
    const float* dwb = (const float*)d_in[10];
    const float* lng = (const float*)d_in[11];
    const float* lnb = (const float*)d_in[12];
    const float* pw  = (const float*)d_in[13];
    const float* rpe = (const float*)d_in[14];

    float* ws = (float*)d_ws;
    const size_t SZ = 786432;           // 2*384*1024 floats
    float* qbuf  = ws;
    float* xs    = ws + 1 * SZ;
    float* abuf  = ws + 2 * SZ;
    float* oconv = ws + 3 * SZ;
    _Float16* khT = (_Float16*)(ws + 4 * SZ);
    _Float16* vhb = (_Float16*)(ws + 5 * SZ);
    float* pos   = ws + 6 * SZ;

    dim3 gqo(16, 12, 2);
    gemm_mfma_qo<<<gqo, 256, 0, stream>>>(Wq, bq, x, qbuf);
    dwconv_kernel<<<768, 256, 0, stream>>>(qbuf, dww, dwb, oconv);
    offset_kernel<<<dim3(12, 4), 256, 0, stream>>>(oconv, lng, lnb, pw, pos);
    sample_kernel<<<3072, 256, 0, stream>>>(x, pos, xs);
    gemm_mfma_kv<<<dim3(16, 12, 4), 256, 0, stream>>>(Wk, bk, Wv, bv, xs, khT, vhb);
    attn_mfma_kernel<<<dim3(64, 24), 256, 0, stream>>>(qbuf, khT, vhb, pos, rpe, abuf);
    gemm_mfma_qo<<<gqo, 256, 0, stream>>>(Wo, bo, abuf, (float*)d_out);
}

// Round 11
// 211.876 us; speedup vs baseline: 1.1047x; 1.1047x over previous
//
#include <hip/hip_runtime.h>
#include <hip/hip_fp16.h>
#include <math.h>

#define HH 32
#define WW 32
#define HWSZ 1024      // H*W
#define CC 384
#define NHEAD 12
#define NGROUP 6
#define HC 32
#define GC 64
#define NS 1024        // n_sample
#define ATTN_SCALE 0.17677669529663687f  // 32^-0.5

typedef _Float16 half8_t __attribute__((ext_vector_type(8)));
typedef _Float16 half4_t __attribute__((ext_vector_type(4)));
typedef _Float16 half2_t __attribute__((ext_vector_type(2)));
typedef float    f4_t    __attribute__((ext_vector_type(4)));

// ---------------------------------------------------------------------------
// MFMA GEMM (fp32 in/out via f16 hi/lo splits, 3 MFMAs per product).
// Y[b,o,n] = sum_c W[o,c] X[b,c,n] + bias[o].  Tile M=32, N=64, BK=32.
// ---------------------------------------------------------------------------
__global__ __launch_bounds__(256) void gemm_mfma_qo(
    const float* __restrict__ W, const float* __restrict__ bias,
    const float* __restrict__ X, float* __restrict__ Y)
{
    const int bz = blockIdx.z;
    const int tm = blockIdx.y * 32;
    const int tn = blockIdx.x * 64;
    const int tid = threadIdx.x;
    const int w = tid >> 6, lane = tid & 63;
    const int quad = lane >> 4, lcol = lane & 15;

    __shared__ _Float16 sWh[32][40], sWl[32][40];   // W tile hi/lo [m][k]
    __shared__ _Float16 sXh[64][40], sXl[64][40];   // X tile hi/lo [n][k]

    const float* Xb = X + (size_t)bz * CC * 1024;
    float* Yb = Y + (size_t)bz * CC * 1024;

    f4_t acc0 = {0.f, 0.f, 0.f, 0.f}, acc1 = {0.f, 0.f, 0.f, 0.f};

    for (int k0 = 0; k0 < CC; k0 += 32) {
        {
            int m = tid >> 3, k4 = (tid & 7) * 4;
            float4 wv = *(const float4*)&W[(size_t)(tm + m) * CC + k0 + k4];
            float vv[4] = {wv.x, wv.y, wv.z, wv.w};
#pragma unroll
            for (int i = 0; i < 4; ++i) {
                _Float16 h = (_Float16)vv[i];
                sWh[m][k4 + i] = h;
                sWl[m][k4 + i] = (_Float16)(vv[i] - (float)h);
            }
        }
        {
            int k = tid >> 3, n8 = (tid & 7) * 8;
            float4 xa = *(const float4*)&Xb[(size_t)(k0 + k) * 1024 + tn + n8];
            float4 xc = *(const float4*)&Xb[(size_t)(k0 + k) * 1024 + tn + n8 + 4];
            float vv[8] = {xa.x, xa.y, xa.z, xa.w, xc.x, xc.y, xc.z, xc.w};
#pragma unroll
            for (int i = 0; i < 8; ++i) {
                _Float16 h = (_Float16)vv[i];
                sXh[n8 + i][k] = h;
                sXl[n8 + i][k] = (_Float16)(vv[i] - (float)h);
            }
        }
        __syncthreads();

        half8_t Ah0 = *(const half8_t*)&sWh[lcol][quad * 8];
        half8_t Al0 = *(const half8_t*)&sWl[lcol][quad * 8];
        half8_t Ah1 = *(const half8_t*)&sWh[16 + lcol][quad * 8];
        half8_t Al1 = *(const half8_t*)&sWl[16 + lcol][quad * 8];
        half8_t Bh  = *(const half8_t*)&sXh[w * 16 + lcol][quad * 8];
        half8_t Bl  = *(const half8_t*)&sXl[w * 16 + lcol][quad * 8];

        acc0 = __builtin_amdgcn_mfma_f32_16x16x32_f16(Ah0, Bl, acc0, 0, 0, 0);
        acc0 = __builtin_amdgcn_mfma_f32_16x16x32_f16(Al0, Bh, acc0, 0, 0, 0);
        acc0 = __builtin_amdgcn_mfma_f32_16x16x32_f16(Ah0, Bh, acc0, 0, 0, 0);
        acc1 = __builtin_amdgcn_mfma_f32_16x16x32_f16(Ah1, Bl, acc1, 0, 0, 0);
        acc1 = __builtin_amdgcn_mfma_f32_16x16x32_f16(Al1, Bh, acc1, 0, 0, 0);
        acc1 = __builtin_amdgcn_mfma_f32_16x16x32_f16(Ah1, Bh, acc1, 0, 0, 0);
        __syncthreads();
    }

#pragma unroll
    for (int r = 0; r < 4; ++r) {
        int m0 = tm + quad * 4 + r;
        Yb[(size_t)m0 * 1024 + tn + w * 16 + lcol]        = acc0[r] + bias[m0];
        Yb[(size_t)(m0 + 16) * 1024 + tn + w * 16 + lcol] = acc1[r] + bias[m0 + 16];
    }
}

// ---------------------------------------------------------------------------
// MFMA K/V projection. V: D[hc][n] = W·X -> vhb [bh][hc][n];
// K: D[n][hc] = X^T·W^T -> khT [bh][n][hc].  f16 outputs.
// ---------------------------------------------------------------------------
__global__ __launch_bounds__(256) void gemm_mfma_kv(
    const float* __restrict__ Wk, const float* __restrict__ bk,
    const float* __restrict__ Wv, const float* __restrict__ bv,
    const float* __restrict__ X,
    _Float16* __restrict__ khT, _Float16* __restrict__ vhb)
{
    const int bz = blockIdx.z >> 1, which = blockIdx.z & 1;
    const int head = blockIdx.y;
    const int tm = head * 32;
    const int tn = blockIdx.x * 64;
    const int tid = threadIdx.x;
    const int w = tid >> 6, lane = tid & 63;
    const int quad = lane >> 4, lcol = lane & 15;
    const int bh = bz * 12 + head;

    const float* W    = which ? Wv : Wk;
    const float* bias = which ? bv : bk;

    __shared__ _Float16 sWh[32][40], sWl[32][40];
    __shared__ _Float16 sXh[64][40], sXl[64][40];

    const float* Xb = X + (size_t)bz * CC * 1024;

    f4_t acc0 = {0.f, 0.f, 0.f, 0.f}, acc1 = {0.f, 0.f, 0.f, 0.f};

    for (int k0 = 0; k0 < CC; k0 += 32) {
        {
            int m = tid >> 3, k4 = (tid & 7) * 4;
            float4 wv = *(const float4*)&W[(size_t)(tm + m) * CC + k0 + k4];
            float vv[4] = {wv.x, wv.y, wv.z, wv.w};
#pragma unroll
            for (int i = 0; i < 4; ++i) {
                _Float16 h = (_Float16)vv[i];
                sWh[m][k4 + i] = h;
                sWl[m][k4 + i] = (_Float16)(vv[i] - (float)h);
            }
        }
        {
            int k = tid >> 3, n8 = (tid & 7) * 8;
            float4 xa = *(const float4*)&Xb[(size_t)(k0 + k) * 1024 + tn + n8];
            float4 xc = *(const float4*)&Xb[(size_t)(k0 + k) * 1024 + tn + n8 + 4];
            float vv[8] = {xa.x, xa.y, xa.z, xa.w, xc.x, xc.y, xc.z, xc.w};
#pragma unroll
            for (int i = 0; i < 8; ++i) {
                _Float16 h = (_Float16)vv[i];
                sXh[n8 + i][k] = h;
                sXl[n8 + i][k] = (_Float16)(vv[i] - (float)h);
            }
        }
        __syncthreads();

        if (which) {
            half8_t Ah0 = *(const half8_t*)&sWh[lcol][quad * 8];
            half8_t Al0 = *(const half8_t*)&sWl[lcol][quad * 8];
            half8_t Ah1 = *(const half8_t*)&sWh[16 + lcol][quad * 8];
            half8_t Al1 = *(const half8_t*)&sWl[16 + lcol][quad * 8];
            half8_t Bh  = *(const half8_t*)&sXh[w * 16 + lcol][quad * 8];
            half8_t Bl  = *(const half8_t*)&sXl[w * 16 + lcol][quad * 8];
            acc0 = __builtin_amdgcn_mfma_f32_16x16x32_f16(Ah0, Bl, acc0, 0, 0, 0);
            acc0 = __builtin_amdgcn_mfma_f32_16x16x32_f16(Al0, Bh, acc0, 0, 0, 0);
            acc0 = __builtin_amdgcn_mfma_f32_16x16x32_f16(Ah0, Bh, acc0, 0, 0, 0);
            acc1 = __builtin_amdgcn_mfma_f32_16x16x32_f16(Ah1, Bl, acc1, 0, 0, 0);
            acc1 = __builtin_amdgcn_mfma_f32_16x16x32_f16(Al1, Bh, acc1, 0, 0, 0);
            acc1 = __builtin_amdgcn_mfma_f32_16x16x32_f16(Ah1, Bh, acc1, 0, 0, 0);
        } else {
            half8_t Ah = *(const half8_t*)&sXh[w * 16 + lcol][quad * 8];
            half8_t Al = *(const half8_t*)&sXl[w * 16 + lcol][quad * 8];
            half8_t Bh0 = *(const half8_t*)&sWh[lcol][quad * 8];
            half8_t Bl0 = *(const half8_t*)&sWl[lcol][quad * 8];
            half8_t Bh1 = *(const half8_t*)&sWh[16 + lcol][quad * 8];
            half8_t Bl1 = *(const half8_t*)&sWl[16 + lcol][quad * 8];
            acc0 = __builtin_amdgcn_mfma_f32_16x16x32_f16(Ah, Bl0, acc0, 0, 0, 0);
            acc0 = __builtin_amdgcn_mfma_f32_16x16x32_f16(Al, Bh0, acc0, 0, 0, 0);
            acc0 = __builtin_amdgcn_mfma_f32_16x16x32_f16(Ah, Bh0, acc0, 0, 0, 0);
            acc1 = __builtin_amdgcn_mfma_f32_16x16x32_f16(Ah, Bl1, acc1, 0, 0, 0);
            acc1 = __builtin_amdgcn_mfma_f32_16x16x32_f16(Al, Bh1, acc1, 0, 0, 0);
            acc1 = __builtin_amdgcn_mfma_f32_16x16x32_f16(Ah, Bh1, acc1, 0, 0, 0);
        }
        __syncthreads();
    }

    if (which) {
#pragma unroll
        for (int r = 0; r < 4; ++r) {
            int hc0 = quad * 4 + r;
            vhb[((size_t)bh * 32 + hc0) * 1024 + tn + w * 16 + lcol] =
                (_Float16)(acc0[r] + bias[tm + hc0]);
            vhb[((size_t)bh * 32 + hc0 + 16) * 1024 + tn + w * 16 + lcol] =
                (_Float16)(acc1[r] + bias[tm + hc0 + 16]);
        }
    } else {
        float bk0 = bias[tm + lcol], bk1 = bias[tm + 16 + lcol];
#pragma unroll
        for (int r = 0; r < 4; ++r) {
            int n = tn + w * 16 + quad * 4 + r;
            khT[((size_t)bh * 1024 + n) * 32 + lcol]      = (_Float16)(acc0[r] + bk0);
            khT[((size_t)bh * 1024 + n) * 32 + 16 + lcol] = (_Float16)(acc1[r] + bk1);
        }
    }
}

// ---------------------------------------------------------------------------
// Depthwise 7x7 conv on q viewed as [12, 64, 32, 32]; zero pad 3.
// ---------------------------------------------------------------------------
__global__ __launch_bounds__(256) void dwconv_kernel(
    const float* __restrict__ q, const float* __restrict__ dww,
    const float* __restrict__ dwb, float* __restrict__ oconv)
{
    const int bc = blockIdx.x;
    const int bg = bc >> 6, c = bc & 63;
    const int b = bg / 6, g = bg % 6;
    const float* plane = q + ((size_t)b * CC + g * 64 + c) * 1024;

    __shared__ float sp[1024];
    __shared__ float sw[49];
    const int tid = threadIdx.x;
    for (int i = tid; i < 1024; i += 256) sp[i] = plane[i];
    if (tid < 49) sw[tid] = dww[c * 49 + tid];
    __syncthreads();

    const float bias = dwb[c];
    for (int i = tid; i < 1024; i += 256) {
        int y = i >> 5, x = i & 31;
        float s = 0.f;
#pragma unroll
        for (int ky = 0; ky < 7; ++ky) {
            int yy = y + ky - 3;
            if (yy < 0 || yy > 31) continue;
#pragma unroll
            for (int kx = 0; kx < 7; ++kx) {
                int xx = x + kx - 3;
                if (xx < 0 || xx > 31) continue;
                s += sp[yy * 32 + xx] * sw[ky * 7 + kx];
            }
        }
        oconv[(size_t)bc * 1024 + i] = s + bias;
    }
}

// ---------------------------------------------------------------------------
// FUSED offset + sample. Grid (16 px-tiles, 12 bg), 256 thr = 4 cgroups x 64px.
// LN(64ch) split 4-way across cgroups (16 erff/thread), tanh offsets -> pos
// (written to global for attn RPE AND kept in LDS), then bilinear-sample the
// block's own 64 channels x 64 px of x -> xs. Kills the pos round-trip and
// one launch; 4x the parallelism of the old 48-block offset kernel.
// ---------------------------------------------------------------------------
__global__ __launch_bounds__(256) void offset_sample_kernel(
    const float* __restrict__ oconv, const float* __restrict__ lng,
    const float* __restrict__ lnb, const float* __restrict__ pw,
    const float* __restrict__ x, float* __restrict__ pos,
    float* __restrict__ xs)
{
    const int bg = blockIdx.y;
    const int px0 = blockIdx.x * 64;
    const int t = threadIdx.x;
    const int cg = t >> 6, pl = t & 63;
    const int px = px0 + pl;
    const int b = bg / 6, g = bg % 6;

    __shared__ float red[4][64];
    __shared__ float spos[64][2];

    const float* base = oconv + ((size_t)bg * 64 + cg * 16) * 1024 + px;
    float col[16];
    float s = 0.f;
#pragma unroll
    for (int i = 0; i < 16; ++i) { col[i] = base[(size_t)i * 1024]; s += col[i]; }
    red[cg][pl] = s;
    __syncthreads();
    float mu = (red[0][pl] + red[1][pl] + red[2][pl] + red[3][pl]) * (1.f / 64.f);
    float v = 0.f;
#pragma unroll
    for (int i = 0; i < 16; ++i) { float d = col[i] - mu; v += d * d; }
    __syncthreads();
    red[cg][pl] = v;
    __syncthreads();
    float inv = rsqrtf((red[0][pl] + red[1][pl] + red[2][pl] + red[3][pl]) * (1.f / 64.f) + 1e-5f);

    float oy = 0.f, ox = 0.f;
#pragma unroll
    for (int i = 0; i < 16; ++i) {
        int c = cg * 16 + i;
        float val = (col[i] - mu) * inv * lng[c] + lnb[c];
        float gl = 0.5f * val * (1.f + erff(val * 0.70710678118654752440f));
        oy += gl * pw[c];
        ox += gl * pw[64 + c];
    }
    __syncthreads();
    red[cg][pl] = oy;
    __syncthreads();
    float oyt = red[0][pl] + red[1][pl] + red[2][pl] + red[3][pl];
    __syncthreads();
    red[cg][pl] = ox;
    __syncthreads();
    if (cg == 0) {
        float oxt = red[0][pl] + red[1][pl] + red[2][pl] + red[3][pl];
        float offy = tanhf(oyt) * (2.0f / 32.0f);
        float offx = tanhf(oxt) * (2.0f / 32.0f);
        int y = px >> 5, xx = px & 31;
        float ry = ((y + 0.5f) / 32.f) * 2.f - 1.f;
        float rx = ((xx + 0.5f) / 32.f) * 2.f - 1.f;
        float py = offy + ry, pxv = offx + rx;
        spos[pl][0] = py; spos[pl][1] = pxv;
        pos[((size_t)bg * 1024 + px) * 2 + 0] = py;
        pos[((size_t)bg * 1024 + px) * 2 + 1] = pxv;
    }
    __syncthreads();

    // ---- sample this block's 64 channels at its 64 pixels ----
    float py = spos[pl][0], pxv = spos[pl][1];
    float gx = (pxv + 1.f) * 0.5f * 31.f;
    float gy = (py + 1.f) * 0.5f * 31.f;
    float x0f = floorf(gx), y0f = floorf(gy);
    float wx = gx - x0f, wy = gy - y0f;
    int x0 = (int)x0f, y0 = (int)y0f;
    float vx0 = ((unsigned)x0 <= 31u) ? 1.f : 0.f;
    float vx1 = ((unsigned)(x0 + 1) <= 31u) ? 1.f : 0.f;
    float vy0 = ((unsigned)y0 <= 31u) ? 1.f : 0.f;
    float vy1 = ((unsigned)(y0 + 1) <= 31u) ? 1.f : 0.f;
    float w00 = (1.f - wx) * (1.f - wy) * vx0 * vy0;
    float w01 = wx * (1.f - wy) * vx1 * vy0;
    float w10 = (1.f - wx) * wy * vx0 * vy1;
    float w11 = wx * wy * vx1 * vy1;
    int xc0 = min(max(x0, 0), 31), xc1 = min(max(x0 + 1, 0), 31);
    int yc0 = min(max(y0, 0), 31), yc1 = min(max(y0 + 1, 0), 31);
    int i00 = yc0 * 32 + xc0, i01 = yc0 * 32 + xc1;
    int i10 = yc1 * 32 + xc0, i11 = yc1 * 32 + xc1;

    const float* xb = x + ((size_t)b * CC + g * 64 + cg * 16) * 1024;
    float* xso = xs + ((size_t)b * CC + g * 64 + cg * 16) * 1024 + px;
#pragma unroll
    for (int i = 0; i < 16; ++i) {
        const float* plane = xb + (size_t)i * 1024;
        xso[(size_t)i * 1024] = plane[i00] * w00 + plane[i01] * w01
                              + plane[i10] * w10 + plane[i11] * w11;
    }
}

// ---------------------------------------------------------------------------
// MFMA flash attention, transposed dataflow (S^T = K·Q^T), K-split 4 waves.
// RPE = half2 pair table {t[y][x], t[y][x+1]} (R9 format: 2 b32 taps/score —
// the R10 scalar-u16 table cost +8us). comb aliases the P slabs.
// ---------------------------------------------------------------------------
__global__ __launch_bounds__(256) void attn_mfma_kernel(
    const float* __restrict__ q, const _Float16* __restrict__ khT,
    const _Float16* __restrict__ vhb, const float* __restrict__ pos,
    const float* __restrict__ rpe, float* __restrict__ out)
{
    const int bh = blockIdx.y;
    const int b = bh / 12, head = bh % 12;
    const int bg = b * 6 + (head >> 1);
    const int mblk = blockIdx.x * 16;      // 16 queries, one image row
    const int tid = threadIdx.x;
    const int w = tid >> 6, lane = tid & 63;
    const int quad = lane >> 4, lcol = lane & 15;

    // LDS: srpe2 @0 (15876B), sqh @15888 (1024B), sp @16912 (4x2304B),
    //      cml @26128 (512B).  comb aliases sp.
    __shared__ __align__(16) char smem[26640];
    half2_t*  srpe2 = (half2_t*)smem;
    _Float16* sqh   = (_Float16*)(smem + 15888);
    _Float16* spw   = (_Float16*)(smem + 16912) + w * (16 * 72);
    float*    cml   = (float*)(smem + 26128);
    float*    comb  = (float*)(smem + 16912);

    const float* rp = rpe + (size_t)head * 3969;
    for (int i = tid; i < 3969; i += 256) {
        int xx = i % 63;
        float v0 = rp[i];
        float v1 = (xx < 62) ? rp[i + 1] : 0.f;
        half2_t hv; hv[0] = (_Float16)v0; hv[1] = (_Float16)v1;
        srpe2[i] = hv;
    }
    {
        const float* qb = q + ((size_t)b * CC + head * 32) * 1024 + mblk;
        for (int i = tid; i < 512; i += 256) {
            int hc = i >> 4, m = i & 15;
            sqh[m * 32 + hc] = (_Float16)qb[(size_t)hc * 1024 + m];
        }
    }
    __syncthreads();

    // Q^T B-frag: B[k=hc=quad*8+j][n=query=lcol]
    half8_t qf = *(const half8_t*)&sqh[lcol * 32 + quad * 8];

    const float qyw = (((mblk >> 5) + 0.5f) * (1.f / 32.f)) * 2.f - 1.f;
    const float qx  = (((mblk & 31) + lcol + 0.5f) * (1.f / 32.f)) * 2.f - 1.f;

    const float2* pgv = (const float2*)(pos + (size_t)bg * 2048);
    const _Float16* khb = khT + (size_t)bh * 1024 * 32;
    const _Float16* vhh = vhb + (size_t)bh * 32 * 1024;

    f4_t o0 = {0.f, 0.f, 0.f, 0.f}, o1 = {0.f, 0.f, 0.f, 0.f};
    float mrun = -3.0e38f, lrun = 0.f;     // per-lane query state

#pragma unroll 1
    for (int c = 0; c < 4; ++c) {
        const int n0 = w * 256 + c * 64;
        f4_t S[4];
#pragma unroll
        for (int t = 0; t < 4; ++t) {
            half8_t kh = *(const half8_t*)&khb[(size_t)(n0 + t * 16 + lcol) * 32 + quad * 8];
            f4_t s = {0.f, 0.f, 0.f, 0.f};
            s = __builtin_amdgcn_mfma_f32_16x16x32_f16(kh, qf, s, 0, 0, 0);
#pragma unroll
            for (int r = 0; r < 4; ++r) {
                int key = n0 + t * 16 + quad * 4 + r;
                float2 pp = pgv[key];
                float gy = (qyw - pp.x) * 15.5f + 31.f;
                float gx = (qx  - pp.y) * 15.5f + 31.f;
                float y0f = floorf(gy), x0f = floorf(gx);
                float wy = gy - y0f, wx = gx - x0f;
                int i00 = (int)y0f * 63 + (int)x0f;
                half2_t p0 = srpe2[i00];
                half2_t p1 = srpe2[i00 + 63];
                float r00 = (float)p0[0], r01 = (float)p0[1];
                float r10 = (float)p1[0], r11 = (float)p1[1];
                float top = r00 + (r01 - r00) * wx;
                float bot = r10 + (r11 - r10) * wx;
                s[r] = s[r] * ATTN_SCALE + top + (bot - top) * wy;
            }
            S[t] = s;
        }

        // online softmax for this chunk (per-lane query; reduce keys)
        float cm = -3.0e38f;
#pragma unroll
        for (int t = 0; t < 4; ++t)
            cm = fmaxf(cm, fmaxf(fmaxf(S[t][0], S[t][1]), fmaxf(S[t][2], S[t][3])));
        cm = fmaxf(cm, __shfl_xor(cm, 16));
        cm = fmaxf(cm, __shfl_xor(cm, 32));
        float mnew = fmaxf(mrun, cm);
        float alpha = __expf(mrun - mnew);
        mrun = mnew;

        float rs = 0.f;
#pragma unroll
        for (int t = 0; t < 4; ++t) {
            float p0 = __expf(S[t][0] - mnew);
            float p1 = __expf(S[t][1] - mnew);
            float p2 = __expf(S[t][2] - mnew);
            float p3 = __expf(S[t][3] - mnew);
            rs += (p0 + p1) + (p2 + p3);
            half4_t h;
            h[0] = (_Float16)p0; h[1] = (_Float16)p1;
            h[2] = (_Float16)p2; h[3] = (_Float16)p3;
            *(half4_t*)&spw[lcol * 72 + t * 16 + quad * 4] = h;   // P^T[query][key]
        }
        rs += __shfl_xor(rs, 16);
        rs += __shfl_xor(rs, 32);
        lrun = lrun * alpha + rs;
        o0 *= alpha; o1 *= alpha;

        // PV: O^T += V^T · P^T  (wave-internal LDS read-back; no barrier)
#pragma unroll
        for (int kp = 0; kp < 2; ++kp) {
            half8_t pb = *(const half8_t*)&spw[lcol * 72 + kp * 32 + quad * 8];
            int nb = n0 + kp * 32 + quad * 8;
            half8_t v0 = *(const half8_t*)&vhh[(size_t)lcol * 1024 + nb];
            half8_t v1 = *(const half8_t*)&vhh[(size_t)(16 + lcol) * 1024 + nb];
            o0 = __builtin_amdgcn_mfma_f32_16x16x32_f16(v0, pb, o0, 0, 0, 0);
            o1 = __builtin_amdgcn_mfma_f32_16x16x32_f16(v1, pb, o1, 0, 0, 0);
        }
    }

    __syncthreads();   // everyone done with their P slab -> alias as comb

    // O^T D-layout: o0[r]=O^T[hc=quad*4+r][query=lcol], o1: hc+16
    *(f4_t*)&comb[(w * 16 + lcol) * 36 + quad * 4]      = o0;
    *(f4_t*)&comb[(w * 16 + lcol) * 36 + 16 + quad * 4] = o1;
    if (quad == 0) {
        cml[(w * 16 + lcol) * 2]     = mrun;
        cml[(w * 16 + lcol) * 2 + 1] = lrun;
    }
    __syncthreads();

#pragma unroll
    for (int i = 0; i < 2; ++i) {
        int idx = tid + i * 256;
        int qq = idx >> 5, hc = idx & 31;
        float m0 = cml[(0 * 16 + qq) * 2], l0 = cml[(0 * 16 + qq) * 2 + 1];
        float m1 = cml[(1 * 16 + qq) * 2], l1 = cml[(1 * 16 + qq) * 2 + 1];
        float m2 = cml[(2 * 16 + qq) * 2], l2 = cml[(2 * 16 + qq) * 2 + 1];
        float m3 = cml[(3 * 16 + qq) * 2], l3 = cml[(3 * 16 + qq) * 2 + 1];
        float ms = fmaxf(fmaxf(m0, m1), fmaxf(m2, m3));
        float e0 = __expf(m0 - ms), e1 = __expf(m1 - ms);
        float e2 = __expf(m2 - ms), e3 = __expf(m3 - ms);
        float L = e0 * l0 + e1 * l1 + e2 * l2 + e3 * l3;
        float o = e0 * comb[(0 * 16 + qq) * 36 + hc]
                + e1 * comb[(1 * 16 + qq) * 36 + hc]
                + e2 * comb[(2 * 16 + qq) * 36 + hc]
                + e3 * comb[(3 * 16 + qq) * 36 + hc];
        out[((size_t)b * CC + head * 32 + hc) * 1024 + mblk + qq] = o / L;
    }
}

// ---------------------------------------------------------------------------
extern "C" void kernel_launch(void* const* d_in, const int* in_sizes, int n_in,
                              void* d_out, int out_size, void* d_ws, size_t ws_size,
                              hipStream_t stream) {
    const float* x   = (const float*)d_in[0];
    const float* Wq  = (const float*)d_in[1];
    const float* bq  = (const float*)d_in[2];
    const float* Wk  = (const float*)d_in[3];
    const float* bk  = (const float*)d_in[4];
    const float* Wv  = (const float*)d_in[5];
    const float* bv  = (const float*)d_in[6];
    const float* Wo  = (const float*)d_in[7];
    const float* bo  = (const float*)d_in[8];
    const float* dww = (const float*)d_in[9];
    const float* dwb = (const float*)d_in[10];
    const float* lng = (const float*)d_in[11];
    const float* lnb = (const float*)d_in[12];
    const float* pw  = (const float*)d_in[13];
    const float* rpe = (const float*)d_in[14];

    float* ws = (float*)d_ws;
    const size_t SZ = 786432;           // 2*384*1024 floats
    float* qbuf  = ws;
    float* xs    = ws + 1 * SZ;
    float* abuf  = ws + 2 * SZ;
    float* oconv = ws + 3 * SZ;
    _Float16* khT = (_Float16*)(ws + 4 * SZ);
    _Float16* vhb = (_Float16*)(ws + 5 * SZ);
    float* pos   = ws + 6 * SZ;

    dim3 gqo(16, 12, 2);
    gemm_mfma_qo<<<gqo, 256, 0, stream>>>(Wq, bq, x, qbuf);
    dwconv_kernel<<<768, 256, 0, stream>>>(qbuf, dww, dwb, oconv);
    offset_sample_kernel<<<dim3(16, 12), 256, 0, stream>>>(oconv, lng, lnb, pw, x, pos, xs);
    gemm_mfma_kv<<<dim3(16, 12, 4), 256, 0, stream>>>(Wk, bk, Wv, bv, xs, khT, vhb);
    attn_mfma_kernel<<<dim3(64, 24), 256, 0, stream>>>(qbuf, khT, vhb, pos, rpe, abuf);
    gemm_mfma_qo<<<gqo, 256, 0, stream>>>(Wo, bo, abuf, (float*)d_out);
}

// Round 12
// 179.482 us; speedup vs baseline: 1.3041x; 1.1805x over previous
//
#include <hip/hip_runtime.h>
#include <hip/hip_fp16.h>
#include <math.h>

#define HH 32
#define WW 32
#define HWSZ 1024      // H*W
#define CC 384
#define NHEAD 12
#define NGROUP 6
#define HC 32
#define GC 64
#define NS 1024        // n_sample
#define ATTN_SCALE 0.17677669529663687f  // 32^-0.5

typedef _Float16 half8_t __attribute__((ext_vector_type(8)));
typedef _Float16 half4_t __attribute__((ext_vector_type(4)));
typedef _Float16 half2_t __attribute__((ext_vector_type(2)));
typedef float    f4_t    __attribute__((ext_vector_type(4)));

// ---------------------------------------------------------------------------
// MFMA GEMM, fp32 out: Y[b,o,n] = sum_c W[o,c] X[b,c,n] + bias[o].
// W pure f16; X pure f16 (XLO=0, q-proj) or f16 hi/lo (XLO=1, o-proj).
// Tile M=32, N=64, BK=32; block 256 thr (4 waves, wave w = n-cols w*16..+15).
// X staging: thread (k=tid>>3, nj=tid&7) stores n=nj+8i -> conflict-free.
// ---------------------------------------------------------------------------
template<int XLO>
__global__ __launch_bounds__(256) void gemm_wx(
    const float* __restrict__ W, const float* __restrict__ bias,
    const float* __restrict__ X, float* __restrict__ Y)
{
    const int bz = blockIdx.z;
    const int tm = blockIdx.y * 32;
    const int tn = blockIdx.x * 64;
    const int tid = threadIdx.x;
    const int w = tid >> 6, lane = tid & 63;
    const int quad = lane >> 4, lcol = lane & 15;

    __shared__ _Float16 sWh[32][40];
    __shared__ _Float16 sXh[64][40];
    __shared__ _Float16 sXl[XLO ? 64 : 1][40];

    const float* Xb = X + (size_t)bz * CC * 1024;
    float* Yb = Y + (size_t)bz * CC * 1024;

    f4_t acc0 = {0.f, 0.f, 0.f, 0.f}, acc1 = {0.f, 0.f, 0.f, 0.f};

    for (int k0 = 0; k0 < CC; k0 += 32) {
        {   // W: 32m x 32k, vector half4 stores
            int m = tid >> 3, k4 = (tid & 7) * 4;
            float4 wv = *(const float4*)&W[(size_t)(tm + m) * CC + k0 + k4];
            half4_t h; h[0] = (_Float16)wv.x; h[1] = (_Float16)wv.y;
            h[2] = (_Float16)wv.z; h[3] = (_Float16)wv.w;
            *(half4_t*)&sWh[m][k4] = h;
        }
        {   // X: 32k x 64n -> [n][k]
            int k = tid >> 3, nj = tid & 7;
            const float* xr = &Xb[(size_t)(k0 + k) * 1024 + tn + nj];
#pragma unroll
            for (int i = 0; i < 8; ++i) {
                float v = xr[8 * i];
                _Float16 h = (_Float16)v;
                sXh[nj + 8 * i][k] = h;
                if (XLO) sXl[nj + 8 * i][k] = (_Float16)(v - (float)h);
            }
        }
        __syncthreads();

        half8_t Ah0 = *(const half8_t*)&sWh[lcol][quad * 8];
        half8_t Ah1 = *(const half8_t*)&sWh[16 + lcol][quad * 8];
        half8_t Bh  = *(const half8_t*)&sXh[w * 16 + lcol][quad * 8];
        acc0 = __builtin_amdgcn_mfma_f32_16x16x32_f16(Ah0, Bh, acc0, 0, 0, 0);
        acc1 = __builtin_amdgcn_mfma_f32_16x16x32_f16(Ah1, Bh, acc1, 0, 0, 0);
        if (XLO) {
            half8_t Bl = *(const half8_t*)&sXl[w * 16 + lcol][quad * 8];
            acc0 = __builtin_amdgcn_mfma_f32_16x16x32_f16(Ah0, Bl, acc0, 0, 0, 0);
            acc1 = __builtin_amdgcn_mfma_f32_16x16x32_f16(Ah1, Bl, acc1, 0, 0, 0);
        }
        __syncthreads();
    }

#pragma unroll
    for (int r = 0; r < 4; ++r) {
        int m0 = tm + quad * 4 + r;
        Yb[(size_t)m0 * 1024 + tn + w * 16 + lcol]        = acc0[r] + bias[m0];
        Yb[(size_t)(m0 + 16) * 1024 + tn + w * 16 + lcol] = acc1[r] + bias[m0 + 16];
    }
}

// ---------------------------------------------------------------------------
// MFMA K/V projection, pure f16 (outputs are f16 anyway — hi/lo was wasted).
//   V (which=1): D[hc][n] = W·X -> vhb [bh][hc][n]
//   K (which=0): D[n][hc] = X^T·W^T -> khT [bh][n][hc]
// ---------------------------------------------------------------------------
__global__ __launch_bounds__(256) void gemm_kv_f16(
    const float* __restrict__ Wk, const float* __restrict__ bk,
    const float* __restrict__ Wv, const float* __restrict__ bv,
    const float* __restrict__ X,
    _Float16* __restrict__ khT, _Float16* __restrict__ vhb)
{
    const int bz = blockIdx.z >> 1, which = blockIdx.z & 1;
    const int head = blockIdx.y;
    const int tm = head * 32;
    const int tn = blockIdx.x * 64;
    const int tid = threadIdx.x;
    const int w = tid >> 6, lane = tid & 63;
    const int quad = lane >> 4, lcol = lane & 15;
    const int bh = bz * 12 + head;

    const float* W    = which ? Wv : Wk;
    const float* bias = which ? bv : bk;

    __shared__ _Float16 sWh[32][40];
    __shared__ _Float16 sXh[64][40];

    const float* Xb = X + (size_t)bz * CC * 1024;

    f4_t acc0 = {0.f, 0.f, 0.f, 0.f}, acc1 = {0.f, 0.f, 0.f, 0.f};

    for (int k0 = 0; k0 < CC; k0 += 32) {
        {
            int m = tid >> 3, k4 = (tid & 7) * 4;
            float4 wv = *(const float4*)&W[(size_t)(tm + m) * CC + k0 + k4];
            half4_t h; h[0] = (_Float16)wv.x; h[1] = (_Float16)wv.y;
            h[2] = (_Float16)wv.z; h[3] = (_Float16)wv.w;
            *(half4_t*)&sWh[m][k4] = h;
        }
        {
            int k = tid >> 3, nj = tid & 7;
            const float* xr = &Xb[(size_t)(k0 + k) * 1024 + tn + nj];
#pragma unroll
            for (int i = 0; i < 8; ++i)
                sXh[nj + 8 * i][k] = (_Float16)xr[8 * i];
        }
        __syncthreads();

        if (which) {   // V: A=W, B=X
            half8_t Ah0 = *(const half8_t*)&sWh[lcol][quad * 8];
            half8_t Ah1 = *(const half8_t*)&sWh[16 + lcol][quad * 8];
            half8_t Bh  = *(const half8_t*)&sXh[w * 16 + lcol][quad * 8];
            acc0 = __builtin_amdgcn_mfma_f32_16x16x32_f16(Ah0, Bh, acc0, 0, 0, 0);
            acc1 = __builtin_amdgcn_mfma_f32_16x16x32_f16(Ah1, Bh, acc1, 0, 0, 0);
        } else {       // K: A=X rows (wave w), B=W col-groups
            half8_t Ah  = *(const half8_t*)&sXh[w * 16 + lcol][quad * 8];
            half8_t Bh0 = *(const half8_t*)&sWh[lcol][quad * 8];
            half8_t Bh1 = *(const half8_t*)&sWh[16 + lcol][quad * 8];
            acc0 = __builtin_amdgcn_mfma_f32_16x16x32_f16(Ah, Bh0, acc0, 0, 0, 0);
            acc1 = __builtin_amdgcn_mfma_f32_16x16x32_f16(Ah, Bh1, acc1, 0, 0, 0);
        }
        __syncthreads();
    }

    if (which) {
#pragma unroll
        for (int r = 0; r < 4; ++r) {
            int hc0 = quad * 4 + r;
            vhb[((size_t)bh * 32 + hc0) * 1024 + tn + w * 16 + lcol] =
                (_Float16)(acc0[r] + bias[tm + hc0]);
            vhb[((size_t)bh * 32 + hc0 + 16) * 1024 + tn + w * 16 + lcol] =
                (_Float16)(acc1[r] + bias[tm + hc0 + 16]);
        }
    } else {
        float bk0 = bias[tm + lcol], bk1 = bias[tm + 16 + lcol];
#pragma unroll
        for (int r = 0; r < 4; ++r) {
            int n = tn + w * 16 + quad * 4 + r;
            khT[((size_t)bh * 1024 + n) * 32 + lcol]      = (_Float16)(acc0[r] + bk0);
            khT[((size_t)bh * 1024 + n) * 32 + 16 + lcol] = (_Float16)(acc1[r] + bk1);
        }
    }
}

// ---------------------------------------------------------------------------
// Depthwise 7x7 conv on q viewed as [12, 64, 32, 32]; zero pad 3.
// ---------------------------------------------------------------------------
__global__ __launch_bounds__(256) void dwconv_kernel(
    const float* __restrict__ q, const float* __restrict__ dww,
    const float* __restrict__ dwb, float* __restrict__ oconv)
{
    const int bc = blockIdx.x;
    const int bg = bc >> 6, c = bc & 63;
    const int b = bg / 6, g = bg % 6;
    const float* plane = q + ((size_t)b * CC + g * 64 + c) * 1024;

    __shared__ float sp[1024];
    __shared__ float sw[49];
    const int tid = threadIdx.x;
    for (int i = tid; i < 1024; i += 256) sp[i] = plane[i];
    if (tid < 49) sw[tid] = dww[c * 49 + tid];
    __syncthreads();

    const float bias = dwb[c];
    for (int i = tid; i < 1024; i += 256) {
        int y = i >> 5, x = i & 31;
        float s = 0.f;
#pragma unroll
        for (int ky = 0; ky < 7; ++ky) {
            int yy = y + ky - 3;
            if (yy < 0 || yy > 31) continue;
#pragma unroll
            for (int kx = 0; kx < 7; ++kx) {
                int xx = x + kx - 3;
                if (xx < 0 || xx > 31) continue;
                s += sp[yy * 32 + xx] * sw[ky * 7 + kx];
            }
        }
        oconv[(size_t)bc * 1024 + i] = s + bias;
    }
}

// ---------------------------------------------------------------------------
// FUSED offset + sample (R11, unchanged).
// ---------------------------------------------------------------------------
__global__ __launch_bounds__(256) void offset_sample_kernel(
    const float* __restrict__ oconv, const float* __restrict__ lng,
    const float* __restrict__ lnb, const float* __restrict__ pw,
    const float* __restrict__ x, float* __restrict__ pos,
    float* __restrict__ xs)
{
    const int bg = blockIdx.y;
    const int px0 = blockIdx.x * 64;
    const int t = threadIdx.x;
    const int cg = t >> 6, pl = t & 63;
    const int px = px0 + pl;
    const int b = bg / 6, g = bg % 6;

    __shared__ float red[4][64];
    __shared__ float spos[64][2];

    const float* base = oconv + ((size_t)bg * 64 + cg * 16) * 1024 + px;
    float col[16];
    float s = 0.f;
#pragma unroll
    for (int i = 0; i < 16; ++i) { col[i] = base[(size_t)i * 1024]; s += col[i]; }
    red[cg][pl] = s;
    __syncthreads();
    float mu = (red[0][pl] + red[1][pl] + red[2][pl] + red[3][pl]) * (1.f / 64.f);
    float v = 0.f;
#pragma unroll
    for (int i = 0; i < 16; ++i) { float d = col[i] - mu; v += d * d; }
    __syncthreads();
    red[cg][pl] = v;
    __syncthreads();
    float inv = rsqrtf((red[0][pl] + red[1][pl] + red[2][pl] + red[3][pl]) * (1.f / 64.f) + 1e-5f);

    float oy = 0.f, ox = 0.f;
#pragma unroll
    for (int i = 0; i < 16; ++i) {
        int c = cg * 16 + i;
        float val = (col[i] - mu) * inv * lng[c] + lnb[c];
        float gl = 0.5f * val * (1.f + erff(val * 0.70710678118654752440f));
        oy += gl * pw[c];
        ox += gl * pw[64 + c];
    }
    __syncthreads();
    red[cg][pl] = oy;
    __syncthreads();
    float oyt = red[0][pl] + red[1][pl] + red[2][pl] + red[3][pl];
    __syncthreads();
    red[cg][pl] = ox;
    __syncthreads();
    if (cg == 0) {
        float oxt = red[0][pl] + red[1][pl] + red[2][pl] + red[3][pl];
        float offy = tanhf(oyt) * (2.0f / 32.0f);
        float offx = tanhf(oxt) * (2.0f / 32.0f);
        int y = px >> 5, xx = px & 31;
        float ry = ((y + 0.5f) / 32.f) * 2.f - 1.f;
        float rx = ((xx + 0.5f) / 32.f) * 2.f - 1.f;
        float py = offy + ry, pxv = offx + rx;
        spos[pl][0] = py; spos[pl][1] = pxv;
        pos[((size_t)bg * 1024 + px) * 2 + 0] = py;
        pos[((size_t)bg * 1024 + px) * 2 + 1] = pxv;
    }
    __syncthreads();

    float py = spos[pl][0], pxv = spos[pl][1];
    float gx = (pxv + 1.f) * 0.5f * 31.f;
    float gy = (py + 1.f) * 0.5f * 31.f;
    float x0f = floorf(gx), y0f = floorf(gy);
    float wx = gx - x0f, wy = gy - y0f;
    int x0 = (int)x0f, y0 = (int)y0f;
    float vx0 = ((unsigned)x0 <= 31u) ? 1.f : 0.f;
    float vx1 = ((unsigned)(x0 + 1) <= 31u) ? 1.f : 0.f;
    float vy0 = ((unsigned)y0 <= 31u) ? 1.f : 0.f;
    float vy1 = ((unsigned)(y0 + 1) <= 31u) ? 1.f : 0.f;
    float w00 = (1.f - wx) * (1.f - wy) * vx0 * vy0;
    float w01 = wx * (1.f - wy) * vx1 * vy0;
    float w10 = (1.f - wx) * wy * vx0 * vy1;
    float w11 = wx * wy * vx1 * vy1;
    int xc0 = min(max(x0, 0), 31), xc1 = min(max(x0 + 1, 0), 31);
    int yc0 = min(max(y0, 0), 31), yc1 = min(max(y0 + 1, 0), 31);
    int i00 = yc0 * 32 + xc0, i01 = yc0 * 32 + xc1;
    int i10 = yc1 * 32 + xc0, i11 = yc1 * 32 + xc1;

    const float* xb = x + ((size_t)b * CC + g * 64 + cg * 16) * 1024;
    float* xso = xs + ((size_t)b * CC + g * 64 + cg * 16) * 1024 + px;
#pragma unroll
    for (int i = 0; i < 16; ++i) {
        const float* plane = xb + (size_t)i * 1024;
        xso[(size_t)i * 1024] = plane[i00] * w00 + plane[i01] * w01
                              + plane[i10] * w10 + plane[i11] * w11;
    }
}

// ---------------------------------------------------------------------------
// MFMA flash attention (R11 structure) + WINDOWED RPE table: per 16-query
// block gy spans <32 rows (|off|<1/16 ⇒ py∈(−1.032,1.032)), so a 35-row
// window provably covers all taps. srpe2 15.9KB -> 8.8KB; LDS 27.1 -> 19.6KB
// -> 8 blocks/CU; all 1536 blocks co-resident (kills the 256-block tail).
// ---------------------------------------------------------------------------
__global__ __launch_bounds__(256) void attn_mfma_kernel(
    const float* __restrict__ q, const _Float16* __restrict__ khT,
    const _Float16* __restrict__ vhb, const float* __restrict__ pos,
    const float* __restrict__ rpe, float* __restrict__ out)
{
    const int bh = blockIdx.y;
    const int b = bh / 12, head = bh % 12;
    const int bg = b * 6 + (head >> 1);
    const int mblk = blockIdx.x * 16;      // 16 queries, one image row
    const int tid = threadIdx.x;
    const int w = tid >> 6, lane = tid & 63;
    const int quad = lane >> 4, lcol = lane & 15;

    // LDS: srpe2 @0 (35*63*4=8820 ->8832), sqh @8832 (1024), sp @9856
    //      (4x2304=9216), cml @19072 (512). comb aliases sp.
    __shared__ __align__(16) char smem[19584];
    half2_t*  srpe2 = (half2_t*)smem;
    _Float16* sqh   = (_Float16*)(smem + 8832);
    _Float16* spw   = (_Float16*)(smem + 9856) + w * (16 * 72);
    float*    cml   = (float*)(smem + 19072);
    float*    comb  = (float*)(smem + 9856);

    const float qyw = (((mblk >> 5) + 0.5f) * (1.f / 32.f)) * 2.f - 1.f;
    // RPE row window: gy = (qyw - py)*15.5 + 31, py in (-1.03125, 1.03125)
    int r0; {
        float gy_lo = (qyw - 1.03125f) * 15.5f + 31.f;
        r0 = (int)floorf(gy_lo);
        r0 = min(max(r0, 0), 28);
    }

    const float* rp = rpe + (size_t)head * 3969;
    for (int i = tid; i < 35 * 63; i += 256) {
        int y = i / 63, xx = i - y * 63;
        int gi = (r0 + y) * 63 + xx;
        float v0 = rp[gi];
        float v1 = (xx < 62) ? rp[gi + 1] : 0.f;
        half2_t hv; hv[0] = (_Float16)v0; hv[1] = (_Float16)v1;
        srpe2[i] = hv;
    }
    {
        const float* qb = q + ((size_t)b * CC + head * 32) * 1024 + mblk;
        for (int i = tid; i < 512; i += 256) {
            int hc = i >> 4, m = i & 15;
            sqh[m * 32 + hc] = (_Float16)qb[(size_t)hc * 1024 + m];
        }
    }
    __syncthreads();

    // Q^T B-frag: B[k=hc=quad*8+j][n=query=lcol]
    half8_t qf = *(const half8_t*)&sqh[lcol * 32 + quad * 8];

    const float qx = (((mblk & 31) + lcol + 0.5f) * (1.f / 32.f)) * 2.f - 1.f;

    const float2* pgv = (const float2*)(pos + (size_t)bg * 2048);
    const _Float16* khb = khT + (size_t)bh * 1024 * 32;
    const _Float16* vhh = vhb + (size_t)bh * 32 * 1024;

    f4_t o0 = {0.f, 0.f, 0.f, 0.f}, o1 = {0.f, 0.f, 0.f, 0.f};
    float mrun = -3.0e38f, lrun = 0.f;     // per-lane query state

#pragma unroll 1
    for (int c = 0; c < 4; ++c) {
        const int n0 = w * 256 + c * 64;
        f4_t S[4];
#pragma unroll
        for (int t = 0; t < 4; ++t) {
            half8_t kh = *(const half8_t*)&khb[(size_t)(n0 + t * 16 + lcol) * 32 + quad * 8];
            f4_t s = {0.f, 0.f, 0.f, 0.f};
            s = __builtin_amdgcn_mfma_f32_16x16x32_f16(kh, qf, s, 0, 0, 0);
#pragma unroll
            for (int r = 0; r < 4; ++r) {
                int key = n0 + t * 16 + quad * 4 + r;
                float2 pp = pgv[key];
                float gy = (qyw - pp.x) * 15.5f + 31.f;
                float gx = (qx  - pp.y) * 15.5f + 31.f;
                float y0f = floorf(gy), x0f = floorf(gx);
                float wy = gy - y0f, wx = gx - x0f;
                int i00 = ((int)y0f - r0) * 63 + (int)x0f;
                half2_t p0 = srpe2[i00];
                half2_t p1 = srpe2[i00 + 63];
                float r00 = (float)p0[0], r01 = (float)p0[1];
                float r10 = (float)p1[0], r11 = (float)p1[1];
                float top = r00 + (r01 - r00) * wx;
                float bot = r10 + (r11 - r10) * wx;
                s[r] = s[r] * ATTN_SCALE + top + (bot - top) * wy;
            }
            S[t] = s;
        }

        // online softmax (per-lane query; reduce across keys)
        float cm = -3.0e38f;
#pragma unroll
        for (int t = 0; t < 4; ++t)
            cm = fmaxf(cm, fmaxf(fmaxf(S[t][0], S[t][1]), fmaxf(S[t][2], S[t][3])));
        cm = fmaxf(cm, __shfl_xor(cm, 16));
        cm = fmaxf(cm, __shfl_xor(cm, 32));
        float mnew = fmaxf(mrun, cm);
        float alpha = __expf(mrun - mnew);
        mrun = mnew;

        float rs = 0.f;
#pragma unroll
        for (int t = 0; t < 4; ++t) {
            float p0 = __expf(S[t][0] - mnew);
            float p1 = __expf(S[t][1] - mnew);
            float p2 = __expf(S[t][2] - mnew);
            float p3 = __expf(S[t][3] - mnew);
            rs += (p0 + p1) + (p2 + p3);
            half4_t h;
            h[0] = (_Float16)p0; h[1] = (_Float16)p1;
            h[2] = (_Float16)p2; h[3] = (_Float16)p3;
            *(half4_t*)&spw[lcol * 72 + t * 16 + quad * 4] = h;   // P^T[query][key]
        }
        rs += __shfl_xor(rs, 16);
        rs += __shfl_xor(rs, 32);
        lrun = lrun * alpha + rs;
        o0 *= alpha; o1 *= alpha;

        // PV: O^T += V^T · P^T  (wave-internal LDS read-back; no barrier)
#pragma unroll
        for (int kp = 0; kp < 2; ++kp) {
            half8_t pb = *(const half8_t*)&spw[lcol * 72 + kp * 32 + quad * 8];
            int nb = n0 + kp * 32 + quad * 8;
            half8_t v0 = *(const half8_t*)&vhh[(size_t)lcol * 1024 + nb];
            half8_t v1 = *(const half8_t*)&vhh[(size_t)(16 + lcol) * 1024 + nb];
            o0 = __builtin_amdgcn_mfma_f32_16x16x32_f16(v0, pb, o0, 0, 0, 0);
            o1 = __builtin_amdgcn_mfma_f32_16x16x32_f16(v1, pb, o1, 0, 0, 0);
        }
    }

    __syncthreads();   // everyone done with their P slab -> alias as comb

    *(f4_t*)&comb[(w * 16 + lcol) * 36 + quad * 4]      = o0;
    *(f4_t*)&comb[(w * 16 + lcol) * 36 + 16 + quad * 4] = o1;
    if (quad == 0) {
        cml[(w * 16 + lcol) * 2]     = mrun;
        cml[(w * 16 + lcol) * 2 + 1] = lrun;
    }
    __syncthreads();

#pragma unroll
    for (int i = 0; i < 2; ++i) {
        int idx = tid + i * 256;
        int qq = idx >> 5, hc = idx & 31;
        float m0 = cml[(0 * 16 + qq) * 2], l0 = cml[(0 * 16 + qq) * 2 + 1];
        float m1 = cml[(1 * 16 + qq) * 2], l1 = cml[(1 * 16 + qq) * 2 + 1];
        float m2 = cml[(2 * 16 + qq) * 2], l2 = cml[(2 * 16 + qq) * 2 + 1];
        float m3 = cml[(3 * 16 + qq) * 2], l3 = cml[(3 * 16 + qq) * 2 + 1];
        float ms = fmaxf(fmaxf(m0, m1), fmaxf(m2, m3));
        float e0 = __expf(m0 - ms), e1 = __expf(m1 - ms);
        float e2 = __expf(m2 - ms), e3 = __expf(m3 - ms);
        float L = e0 * l0 + e1 * l1 + e2 * l2 + e3 * l3;
        float o = e0 * comb[(0 * 16 + qq) * 36 + hc]
                + e1 * comb[(1 * 16 + qq) * 36 + hc]
                + e2 * comb[(2 * 16 + qq) * 36 + hc]
                + e3 * comb[(3 * 16 + qq) * 36 + hc];
        out[((size_t)b * CC + head * 32 + hc) * 1024 + mblk + qq] = o / L;
    }
}

// ---------------------------------------------------------------------------
extern "C" void kernel_launch(void* const* d_in, const int* in_sizes, int n_in,
                              void* d_out, int out_size, void* d_ws, size_t ws_size,
                              hipStream_t stream) {
    const float* x   = (const float*)d_in[0];
    const float* Wq  = (const float*)d_in[1];
    const float* bq  = (const float*)d_in[2];
    const float* Wk  = (const float*)d_in[3];
    const float* bk  = (const float*)d_in[4];
    const float* Wv  = (const float*)d_in[5];
    const float* bv  = (const float*)d_in[6];
    const float* Wo  = (const float*)d_in[7];
    const float* bo  = (const float*)d_in[8];
    const float* dww = (const float*)d_in[9];
    const float* dwb = (const float*)d_in[10];
    const float* lng = (const float*)d_in[11];
    const float* lnb = (const float*)d_in[12];
    const float* pw  = (const float*)d_in[13];
    const float* rpe = (const float*)d_in[14];

    float* ws = (float*)d_ws;
    const size_t SZ = 786432;           // 2*384*1024 floats
    float* qbuf  = ws;
    float* xs    = ws + 1 * SZ;
    float* abuf  = ws + 2 * SZ;
    float* oconv = ws + 3 * SZ;
    _Float16* khT = (_Float16*)(ws + 4 * SZ);
    _Float16* vhb = (_Float16*)(ws + 5 * SZ);
    float* pos   = ws + 6 * SZ;

    dim3 gqo(16, 12, 2);
    gemm_wx<0><<<gqo, 256, 0, stream>>>(Wq, bq, x, qbuf);
    dwconv_kernel<<<768, 256, 0, stream>>>(qbuf, dww, dwb, oconv);
    offset_sample_kernel<<<dim3(16, 12), 256, 0, stream>>>(oconv, lng, lnb, pw, x, pos, xs);
    gemm_kv_f16<<<dim3(16, 12, 4), 256, 0, stream>>>(Wk, bk, Wv, bv, xs, khT, vhb);
    attn_mfma_kernel<<<dim3(64, 24), 256, 0, stream>>>(qbuf, khT, vhb, pos, rpe, abuf);
    gemm_wx<1><<<gqo, 256, 0, stream>>>(Wo, bo, abuf, (float*)d_out);
}

// Round 13
// 170.970 us; speedup vs baseline: 1.3690x; 1.0498x over previous
//
#include <hip/hip_runtime.h>
#include <hip/hip_fp16.h>
#include <math.h>

#define HH 32
#define WW 32
#define HWSZ 1024      // H*W
#define CC 384
#define NHEAD 12
#define NGROUP 6
#define HC 32
#define GC 64
#define NS 1024        // n_sample
#define ATTN_SCALE 0.17677669529663687f  // 32^-0.5

typedef _Float16 half8_t __attribute__((ext_vector_type(8)));
typedef _Float16 half4_t __attribute__((ext_vector_type(4)));
typedef _Float16 half2_t __attribute__((ext_vector_type(2)));
typedef float    f4_t    __attribute__((ext_vector_type(4)));

// ---------------------------------------------------------------------------
// MFMA GEMM, fp32 out: Y[b,o,n] = sum_c W[o,c] X[b,c,n] + bias[o].
// W pure f16; X pure f16 (XLO=0, q-proj) or f16 hi/lo (XLO=1, o-proj).
// Tile M=32, N=64, BK=32; block 256 thr (4 waves, wave w = n-cols w*16..+15).
// ---------------------------------------------------------------------------
template<int XLO>
__global__ __launch_bounds__(256) void gemm_wx(
    const float* __restrict__ W, const float* __restrict__ bias,
    const float* __restrict__ X, float* __restrict__ Y)
{
    const int bz = blockIdx.z;
    const int tm = blockIdx.y * 32;
    const int tn = blockIdx.x * 64;
    const int tid = threadIdx.x;
    const int w = tid >> 6, lane = tid & 63;
    const int quad = lane >> 4, lcol = lane & 15;

    __shared__ _Float16 sWh[32][40];
    __shared__ _Float16 sXh[64][40];
    __shared__ _Float16 sXl[XLO ? 64 : 1][40];

    const float* Xb = X + (size_t)bz * CC * 1024;
    float* Yb = Y + (size_t)bz * CC * 1024;

    f4_t acc0 = {0.f, 0.f, 0.f, 0.f}, acc1 = {0.f, 0.f, 0.f, 0.f};

    for (int k0 = 0; k0 < CC; k0 += 32) {
        {
            int m = tid >> 3, k4 = (tid & 7) * 4;
            float4 wv = *(const float4*)&W[(size_t)(tm + m) * CC + k0 + k4];
            half4_t h; h[0] = (_Float16)wv.x; h[1] = (_Float16)wv.y;
            h[2] = (_Float16)wv.z; h[3] = (_Float16)wv.w;
            *(half4_t*)&sWh[m][k4] = h;
        }
        {
            int k = tid >> 3, nj = tid & 7;
            const float* xr = &Xb[(size_t)(k0 + k) * 1024 + tn + nj];
#pragma unroll
            for (int i = 0; i < 8; ++i) {
                float v = xr[8 * i];
                _Float16 h = (_Float16)v;
                sXh[nj + 8 * i][k] = h;
                if (XLO) sXl[nj + 8 * i][k] = (_Float16)(v - (float)h);
            }
        }
        __syncthreads();

        half8_t Ah0 = *(const half8_t*)&sWh[lcol][quad * 8];
        half8_t Ah1 = *(const half8_t*)&sWh[16 + lcol][quad * 8];
        half8_t Bh  = *(const half8_t*)&sXh[w * 16 + lcol][quad * 8];
        acc0 = __builtin_amdgcn_mfma_f32_16x16x32_f16(Ah0, Bh, acc0, 0, 0, 0);
        acc1 = __builtin_amdgcn_mfma_f32_16x16x32_f16(Ah1, Bh, acc1, 0, 0, 0);
        if (XLO) {
            half8_t Bl = *(const half8_t*)&sXl[w * 16 + lcol][quad * 8];
            acc0 = __builtin_amdgcn_mfma_f32_16x16x32_f16(Ah0, Bl, acc0, 0, 0, 0);
            acc1 = __builtin_amdgcn_mfma_f32_16x16x32_f16(Ah1, Bl, acc1, 0, 0, 0);
        }
        __syncthreads();
    }

#pragma unroll
    for (int r = 0; r < 4; ++r) {
        int m0 = tm + quad * 4 + r;
        Yb[(size_t)m0 * 1024 + tn + w * 16 + lcol]        = acc0[r] + bias[m0];
        Yb[(size_t)(m0 + 16) * 1024 + tn + w * 16 + lcol] = acc1[r] + bias[m0 + 16];
    }
}

// ---------------------------------------------------------------------------
// FUSED MFMA K+V projection (pure f16): X tile staged ONCE per block,
// both products per k-iter.  Grid (16 n-tiles, 12 heads, 2 batches).
//   K: D[n][hc] = X^T·Wk^T -> khT [bh][n][hc]
//   V: D[hc][n] = Wv·X     -> vhb [bh][hc][n]
// ---------------------------------------------------------------------------
__global__ __launch_bounds__(256) void gemm_kv_fused(
    const float* __restrict__ Wk, const float* __restrict__ bk,
    const float* __restrict__ Wv, const float* __restrict__ bv,
    const float* __restrict__ X,
    _Float16* __restrict__ khT, _Float16* __restrict__ vhb)
{
    const int bz = blockIdx.z;
    const int head = blockIdx.y;
    const int tm = head * 32;
    const int tn = blockIdx.x * 64;
    const int tid = threadIdx.x;
    const int w = tid >> 6, lane = tid & 63;
    const int quad = lane >> 4, lcol = lane & 15;
    const int bh = bz * 12 + head;

    __shared__ _Float16 sWk[32][40], sWv[32][40];
    __shared__ _Float16 sXh[64][40];

    const float* Xb = X + (size_t)bz * CC * 1024;

    f4_t ak0 = {0.f, 0.f, 0.f, 0.f}, ak1 = {0.f, 0.f, 0.f, 0.f};
    f4_t av0 = {0.f, 0.f, 0.f, 0.f}, av1 = {0.f, 0.f, 0.f, 0.f};

    for (int k0 = 0; k0 < CC; k0 += 32) {
        {
            int m = tid >> 3, k4 = (tid & 7) * 4;
            float4 wk = *(const float4*)&Wk[(size_t)(tm + m) * CC + k0 + k4];
            float4 wv = *(const float4*)&Wv[(size_t)(tm + m) * CC + k0 + k4];
            half4_t hk; hk[0] = (_Float16)wk.x; hk[1] = (_Float16)wk.y;
            hk[2] = (_Float16)wk.z; hk[3] = (_Float16)wk.w;
            half4_t hv; hv[0] = (_Float16)wv.x; hv[1] = (_Float16)wv.y;
            hv[2] = (_Float16)wv.z; hv[3] = (_Float16)wv.w;
            *(half4_t*)&sWk[m][k4] = hk;
            *(half4_t*)&sWv[m][k4] = hv;
        }
        {
            int k = tid >> 3, nj = tid & 7;
            const float* xr = &Xb[(size_t)(k0 + k) * 1024 + tn + nj];
#pragma unroll
            for (int i = 0; i < 8; ++i)
                sXh[nj + 8 * i][k] = (_Float16)xr[8 * i];
        }
        __syncthreads();

        half8_t Xa = *(const half8_t*)&sXh[w * 16 + lcol][quad * 8];   // A for K, B for V
        half8_t K0 = *(const half8_t*)&sWk[lcol][quad * 8];
        half8_t K1 = *(const half8_t*)&sWk[16 + lcol][quad * 8];
        half8_t V0 = *(const half8_t*)&sWv[lcol][quad * 8];
        half8_t V1 = *(const half8_t*)&sWv[16 + lcol][quad * 8];
        ak0 = __builtin_amdgcn_mfma_f32_16x16x32_f16(Xa, K0, ak0, 0, 0, 0);
        ak1 = __builtin_amdgcn_mfma_f32_16x16x32_f16(Xa, K1, ak1, 0, 0, 0);
        av0 = __builtin_amdgcn_mfma_f32_16x16x32_f16(V0, Xa, av0, 0, 0, 0);
        av1 = __builtin_amdgcn_mfma_f32_16x16x32_f16(V1, Xa, av1, 0, 0, 0);
        __syncthreads();
    }

    {   // K epilogue: [bh][n][hc]
        float bk0 = bk[tm + lcol], bk1 = bk[tm + 16 + lcol];
#pragma unroll
        for (int r = 0; r < 4; ++r) {
            int n = tn + w * 16 + quad * 4 + r;
            khT[((size_t)bh * 1024 + n) * 32 + lcol]      = (_Float16)(ak0[r] + bk0);
            khT[((size_t)bh * 1024 + n) * 32 + 16 + lcol] = (_Float16)(ak1[r] + bk1);
        }
    }
    {   // V epilogue: [bh][hc][n]
#pragma unroll
        for (int r = 0; r < 4; ++r) {
            int hc0 = quad * 4 + r;
            vhb[((size_t)bh * 32 + hc0) * 1024 + tn + w * 16 + lcol] =
                (_Float16)(av0[r] + bv[tm + hc0]);
            vhb[((size_t)bh * 32 + hc0 + 16) * 1024 + tn + w * 16 + lcol] =
                (_Float16)(av1[r] + bv[tm + hc0 + 16]);
        }
    }
}

// ---------------------------------------------------------------------------
// Depthwise 7x7 conv on q viewed as [12, 64, 32, 32]; zero pad 3.
// ---------------------------------------------------------------------------
__global__ __launch_bounds__(256) void dwconv_kernel(
    const float* __restrict__ q, const float* __restrict__ dww,
    const float* __restrict__ dwb, float* __restrict__ oconv)
{
    const int bc = blockIdx.x;
    const int bg = bc >> 6, c = bc & 63;
    const int b = bg / 6, g = bg % 6;
    const float* plane = q + ((size_t)b * CC + g * 64 + c) * 1024;

    __shared__ float sp[1024];
    __shared__ float sw[49];
    const int tid = threadIdx.x;
    for (int i = tid; i < 1024; i += 256) sp[i] = plane[i];
    if (tid < 49) sw[tid] = dww[c * 49 + tid];
    __syncthreads();

    const float bias = dwb[c];
    for (int i = tid; i < 1024; i += 256) {
        int y = i >> 5, x = i & 31;
        float s = 0.f;
#pragma unroll
        for (int ky = 0; ky < 7; ++ky) {
            int yy = y + ky - 3;
            if (yy < 0 || yy > 31) continue;
#pragma unroll
            for (int kx = 0; kx < 7; ++kx) {
                int xx = x + kx - 3;
                if (xx < 0 || xx > 31) continue;
                s += sp[yy * 32 + xx] * sw[ky * 7 + kx];
            }
        }
        oconv[(size_t)bc * 1024 + i] = s + bias;
    }
}

// ---------------------------------------------------------------------------
// FUSED offset + sample, 4-way channel-split (grid z=cs): every block
// computes the full LN/offset for its 64 pixels (cheap, redundant x4) but
// samples only channels [cs*16, cs*16+16) -> 4x parallelism on the heavy
// scattered-load part (16 loads/thread instead of 64).
// ---------------------------------------------------------------------------
__global__ __launch_bounds__(256) void offset_sample_kernel(
    const float* __restrict__ oconv, const float* __restrict__ lng,
    const float* __restrict__ lnb, const float* __restrict__ pw,
    const float* __restrict__ x, float* __restrict__ pos,
    float* __restrict__ xs)
{
    const int bg = blockIdx.y;
    const int cs = blockIdx.z;
    const int px0 = blockIdx.x * 64;
    const int t = threadIdx.x;
    const int cg = t >> 6, pl = t & 63;
    const int px = px0 + pl;
    const int b = bg / 6, g = bg % 6;

    __shared__ float red[4][64];
    __shared__ float spos[64][2];

    const float* base = oconv + ((size_t)bg * 64 + cg * 16) * 1024 + px;
    float col[16];
    float s = 0.f;
#pragma unroll
    for (int i = 0; i < 16; ++i) { col[i] = base[(size_t)i * 1024]; s += col[i]; }
    red[cg][pl] = s;
    __syncthreads();
    float mu = (red[0][pl] + red[1][pl] + red[2][pl] + red[3][pl]) * (1.f / 64.f);
    float v = 0.f;
#pragma unroll
    for (int i = 0; i < 16; ++i) { float d = col[i] - mu; v += d * d; }
    __syncthreads();
    red[cg][pl] = v;
    __syncthreads();
    float inv = rsqrtf((red[0][pl] + red[1][pl] + red[2][pl] + red[3][pl]) * (1.f / 64.f) + 1e-5f);

    float oy = 0.f, ox = 0.f;
#pragma unroll
    for (int i = 0; i < 16; ++i) {
        int c = cg * 16 + i;
        float val = (col[i] - mu) * inv * lng[c] + lnb[c];
        float gl = 0.5f * val * (1.f + erff(val * 0.70710678118654752440f));
        oy += gl * pw[c];
        ox += gl * pw[64 + c];
    }
    __syncthreads();
    red[cg][pl] = oy;
    __syncthreads();
    float oyt = red[0][pl] + red[1][pl] + red[2][pl] + red[3][pl];
    __syncthreads();
    red[cg][pl] = ox;
    __syncthreads();
    if (cg == 0) {
        float oxt = red[0][pl] + red[1][pl] + red[2][pl] + red[3][pl];
        float offy = tanhf(oyt) * (2.0f / 32.0f);
        float offx = tanhf(oxt) * (2.0f / 32.0f);
        int y = px >> 5, xx = px & 31;
        float ry = ((y + 0.5f) / 32.f) * 2.f - 1.f;
        float rx = ((xx + 0.5f) / 32.f) * 2.f - 1.f;
        float py = offy + ry, pxv = offx + rx;
        spos[pl][0] = py; spos[pl][1] = pxv;
        if (cs == 0) {
            pos[((size_t)bg * 1024 + px) * 2 + 0] = py;
            pos[((size_t)bg * 1024 + px) * 2 + 1] = pxv;
        }
    }
    __syncthreads();

    // ---- sample channels cs*16 + cg*4 + [0,4) at pixel px ----
    float py = spos[pl][0], pxv = spos[pl][1];
    float gx = (pxv + 1.f) * 0.5f * 31.f;
    float gy = (py + 1.f) * 0.5f * 31.f;
    float x0f = floorf(gx), y0f = floorf(gy);
    float wx = gx - x0f, wy = gy - y0f;
    int x0 = (int)x0f, y0 = (int)y0f;
    float vx0 = ((unsigned)x0 <= 31u) ? 1.f : 0.f;
    float vx1 = ((unsigned)(x0 + 1) <= 31u) ? 1.f : 0.f;
    float vy0 = ((unsigned)y0 <= 31u) ? 1.f : 0.f;
    float vy1 = ((unsigned)(y0 + 1) <= 31u) ? 1.f : 0.f;
    float w00 = (1.f - wx) * (1.f - wy) * vx0 * vy0;
    float w01 = wx * (1.f - wy) * vx1 * vy0;
    float w10 = (1.f - wx) * wy * vx0 * vy1;
    float w11 = wx * wy * vx1 * vy1;
    int xc0 = min(max(x0, 0), 31), xc1 = min(max(x0 + 1, 0), 31);
    int yc0 = min(max(y0, 0), 31), yc1 = min(max(y0 + 1, 0), 31);
    int i00 = yc0 * 32 + xc0, i01 = yc0 * 32 + xc1;
    int i10 = yc1 * 32 + xc0, i11 = yc1 * 32 + xc1;

    const int c0 = cs * 16 + cg * 4;
    const float* xb = x + ((size_t)b * CC + g * 64 + c0) * 1024;
    float* xso = xs + ((size_t)b * CC + g * 64 + c0) * 1024 + px;
#pragma unroll
    for (int i = 0; i < 4; ++i) {
        const float* plane = xb + (size_t)i * 1024;
        xso[(size_t)i * 1024] = plane[i00] * w00 + plane[i01] * w01
                              + plane[i10] * w10 + plane[i11] * w11;
    }
}

// ---------------------------------------------------------------------------
// MFMA flash attention (R12 structure: transposed S^T=K·Q^T, K-split 4
// waves, windowed RPE 35 rows, comb aliases P slabs) + chunk-level
// PREFETCH: all 8 global loads (4 K-frags + 4 V-frags) issued at chunk top
// so L2 latency overlaps the RPE VALU section.
// ---------------------------------------------------------------------------
__global__ __launch_bounds__(256) void attn_mfma_kernel(
    const float* __restrict__ q, const _Float16* __restrict__ khT,
    const _Float16* __restrict__ vhb, const float* __restrict__ pos,
    const float* __restrict__ rpe, float* __restrict__ out)
{
    const int bh = blockIdx.y;
    const int b = bh / 12, head = bh % 12;
    const int bg = b * 6 + (head >> 1);
    const int mblk = blockIdx.x * 16;      // 16 queries, one image row
    const int tid = threadIdx.x;
    const int w = tid >> 6, lane = tid & 63;
    const int quad = lane >> 4, lcol = lane & 15;

    __shared__ __align__(16) char smem[19584];
    half2_t*  srpe2 = (half2_t*)smem;
    _Float16* sqh   = (_Float16*)(smem + 8832);
    _Float16* spw   = (_Float16*)(smem + 9856) + w * (16 * 72);
    float*    cml   = (float*)(smem + 19072);
    float*    comb  = (float*)(smem + 9856);

    const float qyw = (((mblk >> 5) + 0.5f) * (1.f / 32.f)) * 2.f - 1.f;
    int r0; {
        float gy_lo = (qyw - 1.03125f) * 15.5f + 31.f;
        r0 = (int)floorf(gy_lo);
        r0 = min(max(r0, 0), 28);
    }

    const float* rp = rpe + (size_t)head * 3969;
    for (int i = tid; i < 35 * 63; i += 256) {
        int y = i / 63, xx = i - y * 63;
        int gi = (r0 + y) * 63 + xx;
        float v0 = rp[gi];
        float v1 = (xx < 62) ? rp[gi + 1] : 0.f;
        half2_t hv; hv[0] = (_Float16)v0; hv[1] = (_Float16)v1;
        srpe2[i] = hv;
    }
    {
        const float* qb = q + ((size_t)b * CC + head * 32) * 1024 + mblk;
        for (int i = tid; i < 512; i += 256) {
            int hc = i >> 4, m = i & 15;
            sqh[m * 32 + hc] = (_Float16)qb[(size_t)hc * 1024 + m];
        }
    }
    __syncthreads();

    half8_t qf = *(const half8_t*)&sqh[lcol * 32 + quad * 8];
    const float qx = (((mblk & 31) + lcol + 0.5f) * (1.f / 32.f)) * 2.f - 1.f;

    const float2* pgv = (const float2*)(pos + (size_t)bg * 2048);
    const _Float16* khb = khT + (size_t)bh * 1024 * 32;
    const _Float16* vhh = vhb + (size_t)bh * 32 * 1024;

    f4_t o0 = {0.f, 0.f, 0.f, 0.f}, o1 = {0.f, 0.f, 0.f, 0.f};
    float mrun = -3.0e38f, lrun = 0.f;

#pragma unroll 1
    for (int c = 0; c < 4; ++c) {
        const int n0 = w * 256 + c * 64;

        // ---- prefetch: all global loads for this chunk up front ----
        half8_t khv[4];
#pragma unroll
        for (int t = 0; t < 4; ++t)
            khv[t] = *(const half8_t*)&khb[(size_t)(n0 + t * 16 + lcol) * 32 + quad * 8];
        half8_t vv0[2], vv1[2];
#pragma unroll
        for (int kp = 0; kp < 2; ++kp) {
            int nb = n0 + kp * 32 + quad * 8;
            vv0[kp] = *(const half8_t*)&vhh[(size_t)lcol * 1024 + nb];
            vv1[kp] = *(const half8_t*)&vhh[(size_t)(16 + lcol) * 1024 + nb];
        }

        f4_t S[4];
#pragma unroll
        for (int t = 0; t < 4; ++t) {
            f4_t s = {0.f, 0.f, 0.f, 0.f};
            s = __builtin_amdgcn_mfma_f32_16x16x32_f16(khv[t], qf, s, 0, 0, 0);
#pragma unroll
            for (int r = 0; r < 4; ++r) {
                int key = n0 + t * 16 + quad * 4 + r;
                float2 pp = pgv[key];
                float gy = (qyw - pp.x) * 15.5f + 31.f;
                float gx = (qx  - pp.y) * 15.5f + 31.f;
                float y0f = floorf(gy), x0f = floorf(gx);
                float wy = gy - y0f, wx = gx - x0f;
                int i00 = ((int)y0f - r0) * 63 + (int)x0f;
                half2_t p0 = srpe2[i00];
                half2_t p1 = srpe2[i00 + 63];
                float r00 = (float)p0[0], r01 = (float)p0[1];
                float r10 = (float)p1[0], r11 = (float)p1[1];
                float top = r00 + (r01 - r00) * wx;
                float bot = r10 + (r11 - r10) * wx;
                s[r] = s[r] * ATTN_SCALE + top + (bot - top) * wy;
            }
            S[t] = s;
        }

        float cm = -3.0e38f;
#pragma unroll
        for (int t = 0; t < 4; ++t)
            cm = fmaxf(cm, fmaxf(fmaxf(S[t][0], S[t][1]), fmaxf(S[t][2], S[t][3])));
        cm = fmaxf(cm, __shfl_xor(cm, 16));
        cm = fmaxf(cm, __shfl_xor(cm, 32));
        float mnew = fmaxf(mrun, cm);
        float alpha = __expf(mrun - mnew);
        mrun = mnew;

        float rs = 0.f;
#pragma unroll
        for (int t = 0; t < 4; ++t) {
            float p0 = __expf(S[t][0] - mnew);
            float p1 = __expf(S[t][1] - mnew);
            float p2 = __expf(S[t][2] - mnew);
            float p3 = __expf(S[t][3] - mnew);
            rs += (p0 + p1) + (p2 + p3);
            half4_t h;
            h[0] = (_Float16)p0; h[1] = (_Float16)p1;
            h[2] = (_Float16)p2; h[3] = (_Float16)p3;
            *(half4_t*)&spw[lcol * 72 + t * 16 + quad * 4] = h;
        }
        rs += __shfl_xor(rs, 16);
        rs += __shfl_xor(rs, 32);
        lrun = lrun * alpha + rs;
        o0 *= alpha; o1 *= alpha;

        // PV: O^T += V^T · P^T (wave-internal LDS read-back; no barrier)
#pragma unroll
        for (int kp = 0; kp < 2; ++kp) {
            half8_t pb = *(const half8_t*)&spw[lcol * 72 + kp * 32 + quad * 8];
            o0 = __builtin_amdgcn_mfma_f32_16x16x32_f16(vv0[kp], pb, o0, 0, 0, 0);
            o1 = __builtin_amdgcn_mfma_f32_16x16x32_f16(vv1[kp], pb, o1, 0, 0, 0);
        }
    }

    __syncthreads();

    *(f4_t*)&comb[(w * 16 + lcol) * 36 + quad * 4]      = o0;
    *(f4_t*)&comb[(w * 16 + lcol) * 36 + 16 + quad * 4] = o1;
    if (quad == 0) {
        cml[(w * 16 + lcol) * 2]     = mrun;
        cml[(w * 16 + lcol) * 2 + 1] = lrun;
    }
    __syncthreads();

#pragma unroll
    for (int i = 0; i < 2; ++i) {
        int idx = tid + i * 256;
        int qq = idx >> 5, hc = idx & 31;
        float m0 = cml[(0 * 16 + qq) * 2], l0 = cml[(0 * 16 + qq) * 2 + 1];
        float m1 = cml[(1 * 16 + qq) * 2], l1 = cml[(1 * 16 + qq) * 2 + 1];
        float m2 = cml[(2 * 16 + qq) * 2], l2 = cml[(2 * 16 + qq) * 2 + 1];
        float m3 = cml[(3 * 16 + qq) * 2], l3 = cml[(3 * 16 + qq) * 2 + 1];
        float ms = fmaxf(fmaxf(m0, m1), fmaxf(m2, m3));
        float e0 = __expf(m0 - ms), e1 = __expf(m1 - ms);
        float e2 = __expf(m2 - ms), e3 = __expf(m3 - ms);
        float L = e0 * l0 + e1 * l1 + e2 * l2 + e3 * l3;
        float o = e0 * comb[(0 * 16 + qq) * 36 + hc]
                + e1 * comb[(1 * 16 + qq) * 36 + hc]
                + e2 * comb[(2 * 16 + qq) * 36 + hc]
                + e3 * comb[(3 * 16 + qq) * 36 + hc];
        out[((size_t)b * CC + head * 32 + hc) * 1024 + mblk + qq] = o / L;
    }
}

// ---------------------------------------------------------------------------
extern "C" void kernel_launch(void* const* d_in, const int* in_sizes, int n_in,
                              void* d_out, int out_size, void* d_ws, size_t ws_size,
                              hipStream_t stream) {
    const float* x   = (const float*)d_in[0];
    const float* Wq  = (const float*)d_in[1];
    const float* bq  = (const float*)d_in[2];
    const float* Wk  = (const float*)d_in[3];
    const float* bk  = (const float*)d_in[4];
    const float* Wv  = (const float*)d_in[5];
    const float* bv  = (const float*)d_in[6];
    const float* Wo  = (const float*)d_in[7];
    const float* bo  = (const float*)d_in[8];
    const float* dww = (const float*)d_in[9];
    const float* dwb = (const float*)d_in[10];
    const float* lng = (const float*)d_in[11];
    const float* lnb = (const float*)d_in[12];
    const float* pw  = (const float*)d_in[13];
    const float* rpe = (const float*)d_in[14];

    float* ws = (float*)d_ws;
    const size_t SZ = 786432;           // 2*384*1024 floats
    float* qbuf  = ws;
    float* xs    = ws + 1 * SZ;
    float* abuf  = ws + 2 * SZ;
    float* oconv = ws + 3 * SZ;
    _Float16* khT = (_Float16*)(ws + 4 * SZ);
    _Float16* vhb = (_Float16*)(ws + 5 * SZ);
    float* pos   = ws + 6 * SZ;

    dim3 gqo(16, 12, 2);
    gemm_wx<0><<<gqo, 256, 0, stream>>>(Wq, bq, x, qbuf);
    dwconv_kernel<<<768, 256, 0, stream>>>(qbuf, dww, dwb, oconv);
    offset_sample_kernel<<<dim3(16, 12, 4), 256, 0, stream>>>(oconv, lng, lnb, pw, x, pos, xs);
    gemm_kv_fused<<<dim3(16, 12, 2), 256, 0, stream>>>(Wk, bk, Wv, bv, xs, khT, vhb);
    attn_mfma_kernel<<<dim3(64, 24), 256, 0, stream>>>(qbuf, khT, vhb, pos, rpe, abuf);
    gemm_wx<1><<<gqo, 256, 0, stream>>>(Wo, bo, abuf, (float*)d_out);
}